// Round 8
// baseline (2747.991 us; speedup 1.0000x reference)
//
#include <hip/hip_runtime.h>
#include <math.h>
#include <type_traits>

#define BATCH 8
#define EPS 1e-5f

__device__ __forceinline__ int refl(int p, int n){ return p<0 ? -p : (p>=n ? 2*n-2-p : p); }

// stat layout per layer: stat[(b*C + c)*2] = sum, +1 = sumsq (atomic-accumulated)

// ---------------- conv_in: 3->16, 7x7, reflect pad 3, 512x512 ----------------
// R23: T14 async-stage split (ldreg issue-early, stlds write-late).
__global__ __launch_bounds__(256) void conv7_in_t(const float* __restrict__ in,
    const float* __restrict__ w, const float* __restrict__ bias, float* __restrict__ out,
    float* __restrict__ statOut){
  const int H=512, W=512;
  __shared__ __align__(16) float wsm[3*49*16];
  __shared__ float bsm[16];
  __shared__ __align__(16) float tile[10][264];
  __shared__ float red[4][32];
  for (int t=threadIdx.x; t<2352; t+=256){
    int j = t & 15; int r = t >> 4;
    wsm[t] = w[j*147 + r];
  }
  if (threadIdx.x < 16) bsm[threadIdx.x] = bias[threadIdx.x];

  int bid = blockIdx.x;
  int b  = bid >> 8;
  int yt = (bid >> 1) & 127;  int y0 = yt*4;
  int xh = bid & 1;           int xbase = xh*256;
  int xq = threadIdx.x & 63;  int ty = threadIdx.x >> 6;
  int x0 = xq*4;              int y  = y0 + ty;

  int gy[10];
  #pragma unroll
  for (int r=0;r<10;r++) gy[r] = refl(y0-3+r, H);

  const float* inb = in + (size_t)b*3*H*W;

  float4 sv[3];
  auto ldreg = [&](int ci){
    const float* ipc = inb + (size_t)ci*H*W;
    #pragma unroll
    for (int q=0;q<3;q++){
      int u = threadIdx.x + q*256;
      if (u < 640){
        int r = u >> 6, k = u & 63;
        sv[q] = *(const float4*)(ipc + (size_t)gy[r]*W + xbase + 4*k);
      } else if (u < 700){
        int u2 = u - 640;
        int r = u2 / 6, h = u2 % 6;
        int g = xbase + ((h<3) ? (h-3) : (253+h));
        sv[q].x = ipc[(size_t)gy[r]*W + refl(g, W)];
      }
    }
  };
  auto stlds = [&](){
    #pragma unroll
    for (int q=0;q<3;q++){
      int u = threadIdx.x + q*256;
      if (u < 640){
        int r = u >> 6, k = u & 63;
        *(float4*)&tile[r][4*k+4] = sv[q];
      } else if (u < 700){
        int u2 = u - 640;
        int r = u2 / 6, h = u2 % 6;
        int L = (h<3) ? (1+h) : (257+h);
        tile[r][L] = sv[q].x;
      }
    }
  };

  ldreg(0); stlds();
  __syncthreads();            // wsm, bsm, tile(ci=0) visible

  float acc[16][4];
  #pragma unroll
  for (int j=0;j<16;j++){ float bv=bsm[j];
    #pragma unroll
    for (int p=0;p<4;p++) acc[j][p]=bv; }

  for (int ci=0; ci<3; ++ci){
    if (ci+1 < 3) ldreg(ci+1);          // loads hide under compute
    #pragma unroll
    for (int ky=0; ky<7; ++ky){
      const float* tr = &tile[ty+ky][x0];
      float4 A  = *(const float4*)(tr);
      float4 Bv = *(const float4*)(tr+4);
      float4 Cv = *(const float4*)(tr+8);
      float rv[10] = {A.y,A.z,A.w,Bv.x,Bv.y,Bv.z,Bv.w,Cv.x,Cv.y,Cv.z};
      #pragma unroll
      for (int kx=0; kx<7; ++kx){
        const float4* wp = (const float4*)&wsm[(ci*49+ky*7+kx)*16];
        float4 w0=wp[0], w1=wp[1], w2=wp[2], w3=wp[3];
        float wv[16] = {w0.x,w0.y,w0.z,w0.w, w1.x,w1.y,w1.z,w1.w,
                        w2.x,w2.y,w2.z,w2.w, w3.x,w3.y,w3.z,w3.w};
        #pragma unroll
        for (int p=0;p<4;p++){
          float iv = rv[kx+p];
          #pragma unroll
          for (int j=0;j<16;j++) acc[j][p] = fmaf(iv, wv[j], acc[j][p]);
        }
      }
    }
    __syncthreads();                    // done reading tile
    if (ci+1 < 3){ stlds(); __syncthreads(); }   // tile(ci+1) ready
  }

  float* ob = out + ((size_t)(b*16)*H + y)*W + xbase + x0;
  #pragma unroll
  for (int j=0;j<16;j++){
    float4 v = {acc[j][0],acc[j][1],acc[j][2],acc[j][3]};
    *(float4*)(ob + (size_t)j*H*W) = v;
  }
  float ss[16], qq[16];
  #pragma unroll
  for (int j=0;j<16;j++){
    float a=0.f,c=0.f;
    #pragma unroll
    for (int p=0;p<4;p++){ a+=acc[j][p]; c=fmaf(acc[j][p],acc[j][p],c); }
    ss[j]=a; qq[j]=c;
  }
  #pragma unroll
  for (int o=32;o>0;o>>=1){
    #pragma unroll
    for (int j=0;j<16;j++){ ss[j]+=__shfl_down(ss[j],o); qq[j]+=__shfl_down(qq[j],o); }
  }
  int lane = threadIdx.x & 63, wid = threadIdx.x >> 6;
  if (lane==0){
    #pragma unroll
    for (int j=0;j<16;j++){ red[wid][j]=ss[j]; red[wid][16+j]=qq[j]; }
  }
  __syncthreads();
  if (threadIdx.x < 16){
    int j = threadIdx.x;
    float a = red[0][j]+red[1][j]+red[2][j]+red[3][j];
    float c = red[0][16+j]+red[1][16+j]+red[2][16+j]+red[3][16+j];
    float* sp = &statOut[((size_t)b*16 + j)*2];
    atomicAdd(sp, a); atomicAdd(sp+1, c);
  }
}

// ---------------- conv_out: 16->3, 7x7 reflect, tanh; normalizes input ----------------
// R19 structure + R23 T14 async-stage split.
__global__ __launch_bounds__(256) void conv7_out_t(const float* __restrict__ in,
    const float* __restrict__ w, const float* __restrict__ bias, float* __restrict__ out,
    const float* __restrict__ statIn, const int* __restrict__ imap,
    float* __restrict__ sums, float* __restrict__ cnts){
  const int H=512, W=512;
  __shared__ float msm[16], ism[16];
  __shared__ __align__(16) float tile[14][264];
  __shared__ float ls[96];
  __shared__ float lc[32];
  if (threadIdx.x < 96) ls[threadIdx.x] = 0.f;
  if (threadIdx.x >= 96 && threadIdx.x < 128) lc[threadIdx.x-96] = 0.f;
  if (threadIdx.x < 16){
    const float invHW = 1.f/(512.f*512.f);
    float s  = statIn[((size_t)blockIdx.x>>7)*32 + threadIdx.x*2];
    float s2 = statIn[((size_t)blockIdx.x>>7)*32 + threadIdx.x*2+1];
    float m = s*invHW;
    float v = fmaxf(s2*invHW - m*m, 0.f);
    msm[threadIdx.x] = m; ism[threadIdx.x] = rsqrtf(v + EPS);
  }

  int bid = blockIdx.x;
  int b  = bid >> 7;
  int yt = (bid >> 1) & 63;   int y0 = yt*8;
  int xh = bid & 1;           int xbase = xh*256;
  int xq = threadIdx.x & 63;  int wid = threadIdx.x >> 6;
  int x0 = xq*4;
  int rbase = 2*wid;

  int gy[14];
  #pragma unroll
  for (int r=0;r<14;r++) gy[r] = refl(y0-3+r, H);

  __syncthreads();            // msm/ism, ls/lc visible (ldreg reads msm)

  const float* inb = in + (size_t)b*16*H*W;

  float4 sv[4];
  auto ldreg = [&](int ci){
    const float* ipc = inb + (size_t)ci*H*W;
    float m = msm[ci], is = ism[ci];
    #pragma unroll
    for (int q=0;q<4;q++){
      int u = threadIdx.x + q*256;
      if (u < 896){
        int r = u >> 6, k = u & 63;
        float4 v = *(const float4*)(ipc + (size_t)gy[r]*W + xbase + 4*k);
        v.x = fmaxf((v.x-m)*is, 0.f);
        v.y = fmaxf((v.y-m)*is, 0.f);
        v.z = fmaxf((v.z-m)*is, 0.f);
        v.w = fmaxf((v.w-m)*is, 0.f);
        sv[q] = v;
      } else if (u < 980){
        int u2 = u - 896;
        int r = u2 / 6, h = u2 % 6;
        int g = xbase + ((h<3) ? (h-3) : (253+h));
        float v = ipc[(size_t)gy[r]*W + refl(g, W)];
        sv[q].x = fmaxf((v-m)*is, 0.f);
      }
    }
  };
  auto stlds = [&](){
    #pragma unroll
    for (int q=0;q<4;q++){
      int u = threadIdx.x + q*256;
      if (u < 896){
        int r = u >> 6, k = u & 63;
        *(float4*)&tile[r][4*k+4] = sv[q];
      } else if (u < 980){
        int u2 = u - 896;
        int r = u2 / 6, h = u2 % 6;
        int L = (h<3) ? (1+h) : (257+h);
        tile[r][L] = sv[q].x;
      }
    }
  };

  float acc[3][2][4];
  #pragma unroll
  for (int j=0;j<3;j++){ float bv = bias[j];
    #pragma unroll
    for (int oy=0;oy<2;oy++)
      #pragma unroll
      for (int p=0;p<4;p++) acc[j][oy][p]=bv; }

  ldreg(0); stlds();
  __syncthreads();            // tile(ci=0) ready

  float wbuf[2][21];
  for (int ci=0; ci<16; ++ci){
    if (ci+1 < 16) ldreg(ci+1);        // loads hide under compute
    #pragma unroll
    for (int s=0;s<8;++s){
      const float* tr = &tile[rbase+s][x0];
      float4 A  = *(const float4*)(tr);
      float4 Bv = *(const float4*)(tr+4);
      float4 Cv = *(const float4*)(tr+8);
      float rv[10] = {A.y,A.z,A.w,Bv.x,Bv.y,Bv.z,Bv.w,Cv.x,Cv.y,Cv.z};
      if (s < 7){
        #pragma unroll
        for (int j=0;j<3;j++){
          const float* wj = w + j*784 + ci*49 + s*7;
          #pragma unroll
          for (int kx=0;kx<7;kx++) wbuf[s&1][kx*3+j] = wj[kx];
        }
      }
      if (s >= 1){
        #pragma unroll
        for (int kx=0;kx<7;kx++){
          float w0=wbuf[(s-1)&1][kx*3], w1=wbuf[(s-1)&1][kx*3+1], w2=wbuf[(s-1)&1][kx*3+2];
          #pragma unroll
          for (int p=0;p<4;p++){
            float iv = rv[kx+p];
            acc[0][1][p] = fmaf(iv, w0, acc[0][1][p]);
            acc[1][1][p] = fmaf(iv, w1, acc[1][1][p]);
            acc[2][1][p] = fmaf(iv, w2, acc[2][1][p]);
          }
        }
      }
      if (s < 7){
        #pragma unroll
        for (int kx=0;kx<7;kx++){
          float w0=wbuf[s&1][kx*3], w1=wbuf[s&1][kx*3+1], w2=wbuf[s&1][kx*3+2];
          #pragma unroll
          for (int p=0;p<4;p++){
            float iv = rv[kx+p];
            acc[0][0][p] = fmaf(iv, w0, acc[0][0][p]);
            acc[1][0][p] = fmaf(iv, w1, acc[1][0][p]);
            acc[2][0][p] = fmaf(iv, w2, acc[2][0][p]);
          }
        }
      }
    }
    __syncthreads();                    // done reading tile
    if (ci+1 < 16){ stlds(); __syncthreads(); }   // tile(ci+1) ready
  }

  #pragma unroll
  for (int j=0;j<3;j++)
    #pragma unroll
    for (int oy=0;oy<2;oy++)
      #pragma unroll
      for (int p=0;p<4;p++) acc[j][oy][p] = tanhf(acc[j][oy][p]);

  #pragma unroll
  for (int oy=0;oy<2;oy++){
    int y = y0 + rbase + oy;
    float* ob = out + ((size_t)(b*3)*H + y)*W + xbase + x0;
    #pragma unroll
    for (int j=0;j<3;j++){
      float4 v0 = {acc[j][oy][0],acc[j][oy][1],acc[j][oy][2],acc[j][oy][3]};
      *(float4*)(ob + (size_t)j*H*W) = v0;
    }
  }

  #pragma unroll
  for (int oy=0;oy<2;oy++){
    int y = y0 + rbase + oy;
    const int* mb = imap + ((size_t)b*H + y)*W + xbase + x0;
    int4 i0 = *(const int4*)(mb);
    int im[4] = {i0.x,i0.y,i0.z,i0.w};
    #pragma unroll
    for (int p=0;p<4;p++){
      int id = im[p];
      atomicAdd(&ls[id*3+0], acc[0][oy][p]);
      atomicAdd(&ls[id*3+1], acc[1][oy][p]);
      atomicAdd(&ls[id*3+2], acc[2][oy][p]);
      atomicAdd(&lc[id], 1.0f);
    }
  }
  __syncthreads();
  if (threadIdx.x < 96) atomicAdd(&sums[b*96+threadIdx.x], ls[threadIdx.x]);
  if (threadIdx.x >= 96 && threadIdx.x < 128) atomicAdd(&cnts[b*32+threadIdx.x-96], lc[threadIdx.x-96]);
}

// ---------------- 3x3 stride-2 conv, WIDE 64x16 tile, 4 cols/thread (R21) ----------------
// R22: tile-index INNERMOST in bid (cgi outermost). All CG blocks sharing an input slab
// get bid = tile (mod NT), NT % 8 == 0 -> same XCD -> slab fetched from HBM once, rest L2.
template<int CIN, int COT>
__global__ __launch_bounds__(256,4) void conv3s2_w64(const float* __restrict__ in,
    const float* __restrict__ w, const float* __restrict__ bias, float* __restrict__ out,
    int Hin, int Win, const float* __restrict__ statIn, float* __restrict__ statOut){
  const int Cout = 2*CIN;
  const int TSTR = 136, ODD = 68;        // even[0..63], odd[68..132]
  __shared__ float msm[CIN], ism[CIN];
  __shared__ __align__(16) float tile[2][33*TSTR];   // 35.9 KB
  __shared__ float red[4][2*COT];
  int Hout = Hin>>1, Wout = Win>>1;
  int xtn = Wout>>6, ytn = Hout>>4;
  int NT = BATCH*xtn*ytn;                // multiple of 8
  int bid = blockIdx.x;
  int t = bid % NT; int cgi = bid / NT;  // R22: tile innermost -> XCD locality
  int xt  = t % xtn;  t /= xtn;
  int yt  = t % ytn;  int b = t / ytn;
  int co0 = cgi*COT;
  int X0 = xt<<6, Y0 = yt<<4;
  int IY0 = 2*Y0-1, GX = X0<<1;
  {
    float invHW = 1.f/(float)(Hin*Win);
    for (int t2=threadIdx.x; t2<CIN; t2+=256){
      float s  = statIn[((size_t)b*CIN + t2)*2];
      float s2 = statIn[((size_t)b*CIN + t2)*2+1];
      float m = s*invHW;
      float v = fmaxf(s2*invHW - m*m, 0.f);
      msm[t2] = m; ism[t2] = rsqrtf(v + EPS);
    }
  }
  __syncthreads();
  const float* inb = in + (size_t)b*CIN*Hin*Win;
  int xx = threadIdx.x & 15, ys = threadIdx.x >> 4;

  float4 vv[5];
  auto ld = [&](int ci){
    const float* ip = inb + (size_t)ci*Hin*Win;
    float m = msm[ci], is = ism[ci];
    #pragma unroll
    for (int q=0;q<5;q++){
      int u = threadIdx.x + q*256;
      if (u < 1089){
        int r = u/33, k = u - r*33;
        int iy = IY0 + r;
        bool okY = (unsigned)iy < (unsigned)Hin;
        if (k < 32){
          float4 v = {0.f,0.f,0.f,0.f};
          if (okY){
            v = *(const float4*)(ip + (size_t)iy*Win + GX + 4*k);
            v.x = fmaxf((v.x-m)*is, 0.f);
            v.y = fmaxf((v.y-m)*is, 0.f);
            v.z = fmaxf((v.z-m)*is, 0.f);
            v.w = fmaxf((v.w-m)*is, 0.f);
          }
          vv[q] = v;
        } else {
          float hv = 0.f;
          if (okY && X0 > 0) hv = fmaxf((ip[(size_t)iy*Win + GX-1]-m)*is, 0.f);
          vv[q].x = hv;
        }
      }
    }
  };
  auto st = [&](int buf){
    float* tb = tile[buf];
    #pragma unroll
    for (int q=0;q<5;q++){
      int u = threadIdx.x + q*256;
      if (u < 1089){
        int r = u/33, k = u - r*33;
        float* row = tb + r*TSTR;
        if (k < 32){
          float4 v = vv[q];
          float2 e = {v.x, v.z};
          *(float2*)(row + 2*k) = e;
          row[ODD + 2*k+1] = v.y;
          row[ODD + 2*k+2] = v.w;
        } else {
          row[ODD] = vv[q].x;
        }
      }
    }
  };

  float acc[COT][4];
  #pragma unroll
  for (int j=0;j<COT;j++){ float bv = bias[co0+j];
    #pragma unroll
    for (int p=0;p<4;p++) acc[j][p]=bv; }

  ld(0); st(0);
  for (int ci=0; ci<CIN; ++ci){
    __syncthreads();
    if (ci+1 < CIN) ld(ci+1);
    {
      const float* tb = tile[ci&1];
      float ev[3][4], od[3][5];
      #pragma unroll
      for (int ky=0;ky<3;ky++){
        const float* rowp = tb + (2*ys+ky)*TSTR;
        float4 e4 = *(const float4*)(rowp + 4*xx);
        float4 o4 = *(const float4*)(rowp + ODD + 4*xx);
        float o1  = rowp[ODD + 4*xx + 4];
        ev[ky][0]=e4.x; ev[ky][1]=e4.y; ev[ky][2]=e4.z; ev[ky][3]=e4.w;
        od[ky][0]=o4.x; od[ky][1]=o4.y; od[ky][2]=o4.z; od[ky][3]=o4.w; od[ky][4]=o1;
      }
      #pragma unroll
      for (int j=0;j<COT;j++){
        const float* wj = w + ((size_t)(co0+j)*CIN + ci)*9;   // uniform -> s_load
        float wk[9];
        #pragma unroll
        for (int k=0;k<9;k++) wk[k] = wj[k];
        #pragma unroll
        for (int p=0;p<4;p++){
          #pragma unroll
          for (int ky=0;ky<3;ky++){
            acc[j][p] = fmaf(od[ky][p],   wk[ky*3+0], acc[j][p]);
            acc[j][p] = fmaf(ev[ky][p],   wk[ky*3+1], acc[j][p]);
            acc[j][p] = fmaf(od[ky][p+1], wk[ky*3+2], acc[j][p]);
          }
        }
      }
    }
    if (ci+1 < CIN) st((ci+1)&1);
  }

  float* ob = out + ((size_t)b*Cout + co0)*Hout*Wout + (size_t)(Y0+ys)*Wout + X0 + 4*xx;
  #pragma unroll
  for (int j=0;j<COT;j++){
    float4 v = {acc[j][0],acc[j][1],acc[j][2],acc[j][3]};
    *(float4*)(ob + (size_t)j*Hout*Wout) = v;
  }
  // ---- stats ----
  float ss[COT], qq[COT];
  #pragma unroll
  for (int j=0;j<COT;j++){
    float a=0.f,c=0.f;
    #pragma unroll
    for (int p=0;p<4;p++){ a+=acc[j][p]; c=fmaf(acc[j][p],acc[j][p],c); }
    ss[j]=a; qq[j]=c;
  }
  #pragma unroll
  for (int o=32;o>0;o>>=1){
    #pragma unroll
    for (int j=0;j<COT;j++){ ss[j]+=__shfl_down(ss[j],o); qq[j]+=__shfl_down(qq[j],o); }
  }
  int lane = threadIdx.x & 63, wid = threadIdx.x >> 6;
  if (lane==0){
    #pragma unroll
    for (int j=0;j<COT;j++){ red[wid][j]=ss[j]; red[wid][COT+j]=qq[j]; }
  }
  __syncthreads();
  if (threadIdx.x < COT){
    int j = threadIdx.x;
    float a = red[0][j]+red[1][j]+red[2][j]+red[3][j];
    float c = red[0][COT+j]+red[1][COT+j]+red[2][COT+j]+red[3][COT+j];
    float* sp = &statOut[((size_t)b*Cout + co0 + j)*2];
    atomicAdd(sp, a); atomicAdd(sp+1, c);
  }
}

// ---------------- 3x3 stride-2 conv, 32x16 tile (R20; d3). R22 XCD-local decomposition ----------------
template<int CIN, int COT>
__global__ __launch_bounds__(256,4) void conv3s2_lds(const float* __restrict__ in,
    const float* __restrict__ w, const float* __restrict__ bias, float* __restrict__ out,
    int Hin, int Win, const float* __restrict__ statIn, float* __restrict__ statOut){
  const int Cout = 2*CIN;
  const int TSTR = 72;
  __shared__ float msm[CIN], ism[CIN];
  __shared__ __align__(16) float tile[2][33*TSTR];
  __shared__ float red[4][2*COT];
  int Hout = Hin>>1, Wout = Win>>1;
  int xtn = Wout>>5, ytn = Hout>>4;
  int NT = BATCH*xtn*ytn;                // multiple of 8
  int bid = blockIdx.x;
  int t = bid % NT; int cgi = bid / NT;  // R22: tile innermost -> XCD locality
  int xt  = t % xtn;  t /= xtn;
  int yt  = t % ytn;  int b = t / ytn;
  int co0 = cgi*COT;
  int X0 = xt<<5, Y0 = yt<<4;
  int IY0 = 2*Y0-1, GX = X0<<1;
  {
    float invHW = 1.f/(float)(Hin*Win);
    for (int t2=threadIdx.x; t2<CIN; t2+=256){
      float s  = statIn[((size_t)b*CIN + t2)*2];
      float s2 = statIn[((size_t)b*CIN + t2)*2+1];
      float m = s*invHW;
      float v = fmaxf(s2*invHW - m*m, 0.f);
      msm[t2] = m; ism[t2] = rsqrtf(v + EPS);
    }
  }
  __syncthreads();
  const float* inb = in + (size_t)b*CIN*Hin*Win;
  int xx = threadIdx.x & 31, ys = threadIdx.x >> 5;

  float4 vv[3]; float hh[3];
  auto ld = [&](int ci){
    const float* ip = inb + (size_t)ci*Hin*Win;
    float m = msm[ci], is = ism[ci];
    #pragma unroll
    for (int q=0;q<3;q++){
      int u = threadIdx.x + q*256;
      if (u < 561){
        int r = u/17, k = u - r*17;
        int iy = IY0 + r;
        bool okY = (unsigned)iy < (unsigned)Hin;
        if (k < 16){
          float4 v = {0.f,0.f,0.f,0.f};
          if (okY){
            v = *(const float4*)(ip + (size_t)iy*Win + GX + 4*k);
            v.x = fmaxf((v.x-m)*is, 0.f);
            v.y = fmaxf((v.y-m)*is, 0.f);
            v.z = fmaxf((v.z-m)*is, 0.f);
            v.w = fmaxf((v.w-m)*is, 0.f);
          }
          vv[q] = v;
        } else {
          float hv = 0.f;
          if (okY && X0 > 0) hv = fmaxf((ip[(size_t)iy*Win + GX-1]-m)*is, 0.f);
          hh[q] = hv;
        }
      }
    }
  };
  auto st = [&](int buf){
    float* tb = tile[buf];
    #pragma unroll
    for (int q=0;q<3;q++){
      int u = threadIdx.x + q*256;
      if (u < 561){
        int r = u/17, k = u - r*17;
        float* row = tb + r*TSTR;
        if (k < 16){
          float4 v = vv[q];
          row[2*k]        = v.x;
          row[2*k+1]      = v.z;
          row[36+2*k+1]   = v.y;
          row[36+2*k+2]   = v.w;
        } else {
          row[36] = hh[q];
        }
      }
    }
  };

  float acc[COT][2];
  #pragma unroll
  for (int j=0;j<COT;j++){ float bv = bias[co0+j]; acc[j][0]=bv; acc[j][1]=bv; }

  ld(0); st(0);
  for (int ci=0; ci<CIN; ++ci){
    __syncthreads();
    if (ci+1 < CIN) ld(ci+1);
    {
      const float* tb = tile[ci&1];
      float rv[2][3][3];
      #pragma unroll
      for (int g=0;g<2;g++){
        int rb = (ys + (g<<3))<<1;
        #pragma unroll
        for (int ky=0;ky<3;ky++){
          const float* er = tb + (rb+ky)*TSTR;
          const float* od = er + 36;
          rv[g][ky][0]=od[xx]; rv[g][ky][1]=er[xx]; rv[g][ky][2]=od[xx+1];
        }
      }
      #pragma unroll
      for (int j=0;j<COT;j++){
        const float* wj = w + ((size_t)(co0+j)*CIN + ci)*9;   // uniform -> s_load
        float wk[9];
        #pragma unroll
        for (int k=0;k<9;k++) wk[k] = wj[k];
        #pragma unroll
        for (int g=0;g<2;g++)
          #pragma unroll
          for (int ky=0;ky<3;ky++)
            #pragma unroll
            for (int kx=0;kx<3;kx++)
              acc[j][g] = fmaf(rv[g][ky][kx], wk[ky*3+kx], acc[j][g]);
      }
    }
    if (ci+1 < CIN) st((ci+1)&1);
  }

  float* ob = out + ((size_t)b*Cout + co0)*Hout*Wout;
  #pragma unroll
  for (int j=0;j<COT;j++)
    #pragma unroll
    for (int g=0;g<2;g++){
      int oy = ys + (g<<3);
      ob[(size_t)j*Hout*Wout + (Y0+oy)*Wout + X0 + xx] = acc[j][g];
    }
  // ---- stats ----
  float ss[COT], qq[COT];
  #pragma unroll
  for (int j=0;j<COT;j++){
    float a = acc[j][0] + acc[j][1];
    float c = fmaf(acc[j][0],acc[j][0], acc[j][1]*acc[j][1]);
    ss[j]=a; qq[j]=c;
  }
  #pragma unroll
  for (int o=32;o>0;o>>=1){
    #pragma unroll
    for (int j=0;j<COT;j++){ ss[j]+=__shfl_down(ss[j],o); qq[j]+=__shfl_down(qq[j],o); }
  }
  int lane = threadIdx.x & 63, wid = threadIdx.x >> 6;
  if (lane==0){
    #pragma unroll
    for (int j=0;j<COT;j++){ red[wid][j]=ss[j]; red[wid][COT+j]=qq[j]; }
  }
  __syncthreads();
  if (threadIdx.x < COT){
    int j = threadIdx.x;
    float a = red[0][j]+red[1][j]+red[2][j]+red[3][j];
    float c = red[0][COT+j]+red[1][COT+j]+red[2][COT+j]+red[3][COT+j];
    float* sp = &statOut[((size_t)b*Cout + co0 + j)*2];
    atomicAdd(sp, a); atomicAdd(sp+1, c);
  }
}

// ---------------- tconv k=3 s=2 p=1 op=1; LDS-staged. R22 XCD-local decomposition ----------------
template<int CIN, int COT>
__global__ __launch_bounds__(256,4) void tconv3_lds(const float* __restrict__ in,
    const float* __restrict__ w, const float* __restrict__ bias, float* __restrict__ out,
    int Hin, int Win, const float* __restrict__ statIn, float* __restrict__ statOut){
  const int Cout = CIN/2;
  const int TSTR = 36;
  __shared__ float msm[CIN], ism[CIN];
  __shared__ __align__(16) float tile[2][17*TSTR];
  __shared__ float red[4][2*COT];
  int Hout = Hin<<1, Wout = Win<<1;
  int xtn = Win>>5, ytn = Hin>>4;
  int NT = BATCH*xtn*ytn;                // multiple of 8
  int bid = blockIdx.x;
  int t = bid % NT; int cgi = bid / NT;  // R22: tile innermost -> XCD locality
  int xt  = t % xtn;  t /= xtn;
  int yt  = t % ytn;  int b = t / ytn;
  int co0 = cgi*COT;
  int X0 = xt<<5, Y0 = yt<<4;
  {
    float invHW = 1.f/(float)(Hin*Win);
    for (int t2=threadIdx.x; t2<CIN; t2+=256){
      float s  = statIn[((size_t)b*CIN + t2)*2];
      float s2 = statIn[((size_t)b*CIN + t2)*2+1];
      float m = s*invHW;
      float v = fmaxf(s2*invHW - m*m, 0.f);
      msm[t2] = m; ism[t2] = rsqrtf(v + EPS);
    }
  }
  __syncthreads();
  const float* inb = in + (size_t)b*CIN*Hin*Win;
  int xx = threadIdx.x & 31, ys = threadIdx.x >> 5;

  float4 sv; float sh;
  auto ld = [&](int ci){
    const float* ip = inb + (size_t)ci*Hin*Win;
    float m = msm[ci], is = ism[ci];
    int u = threadIdx.x;
    if (u < 153){
      int r = u/9, k = u - r*9;
      int iy = Y0 + r;
      bool okY = iy < Hin;
      if (k < 8){
        float4 v = {0.f,0.f,0.f,0.f};
        if (okY){
          v = *(const float4*)(ip + (size_t)iy*Win + X0 + 4*k);
          v.x = fmaxf((v.x-m)*is, 0.f);
          v.y = fmaxf((v.y-m)*is, 0.f);
          v.z = fmaxf((v.z-m)*is, 0.f);
          v.w = fmaxf((v.w-m)*is, 0.f);
        }
        sv = v;
      } else {
        float hv = 0.f;
        int xc = X0 + 32;
        if (okY && xc < Win) hv = fmaxf((ip[(size_t)iy*Win + xc]-m)*is, 0.f);
        sh = hv;
      }
    }
  };
  auto st = [&](int buf){
    int u = threadIdx.x;
    if (u < 153){
      int r = u/9, k = u - r*9;
      if (k < 8) *(float4*)(tile[buf] + r*TSTR + 4*k) = sv;
      else tile[buf][r*TSTR + 32] = sh;
    }
  };

  float acc[COT][2][2][2];
  #pragma unroll
  for (int j=0;j<COT;j++){ float bv = bias[co0+j];
    #pragma unroll
    for (int g=0;g<2;g++)
      #pragma unroll
      for (int oy=0;oy<2;oy++){ acc[j][g][oy][0]=bv; acc[j][g][oy][1]=bv; } }

  ld(0); st(0);
  for (int ci=0; ci<CIN; ++ci){
    __syncthreads();
    if (ci+1 < CIN) ld(ci+1);
    {
      const float* tb = tile[ci&1];
      float v[2][2][2];
      #pragma unroll
      for (int g=0;g<2;g++){
        int rb = ys + (g<<3);
        const float* t0 = tb + rb*TSTR + xx;
        v[g][0][0]=t0[0]; v[g][0][1]=t0[1];
        v[g][1][0]=t0[TSTR]; v[g][1][1]=t0[TSTR+1];
      }
      #pragma unroll
      for (int j=0;j<COT;j++){
        const float* wj = w + ((size_t)ci*Cout + co0+j)*9;   // uniform -> s_load
        float wk[9];
        #pragma unroll
        for (int k=0;k<9;k++) wk[k] = wj[k];
        #pragma unroll
        for (int g=0;g<2;g++){
          float v00=v[g][0][0], v01=v[g][0][1], v10=v[g][1][0], v11=v[g][1][1];
          acc[j][g][0][0] = fmaf(v00, wk[4], acc[j][g][0][0]);
          acc[j][g][0][1] = fmaf(v00, wk[5], fmaf(v01, wk[3], acc[j][g][0][1]));
          acc[j][g][1][0] = fmaf(v00, wk[7], fmaf(v10, wk[1], acc[j][g][1][0]));
          acc[j][g][1][1] = fmaf(v00, wk[8], fmaf(v01, wk[6],
                             fmaf(v10, wk[2], fmaf(v11, wk[0], acc[j][g][1][1]))));
        }
      }
    }
    if (ci+1 < CIN) st((ci+1)&1);
  }

  float* ob = out + ((size_t)b*Cout + co0)*Hout*Wout;
  #pragma unroll
  for (int j=0;j<COT;j++)
    #pragma unroll
    for (int g=0;g<2;g++)
      #pragma unroll
      for (int oy=0;oy<2;oy++){
        int orow = 2*(Y0 + ys + (g<<3)) + oy;
        float2 v2 = {acc[j][g][oy][0], acc[j][g][oy][1]};
        *(float2*)(ob + (size_t)j*Hout*Wout + (size_t)orow*Wout + 2*(X0+xx)) = v2;
      }
  // ---- stats ----
  float ss[COT], qq[COT];
  #pragma unroll
  for (int j=0;j<COT;j++){
    float a=0.f,c=0.f;
    #pragma unroll
    for (int g=0;g<2;g++)
      #pragma unroll
      for (int oy=0;oy<2;oy++)
        #pragma unroll
        for (int ox=0;ox<2;ox++){ float u=acc[j][g][oy][ox]; a+=u; c=fmaf(u,u,c); }
    ss[j]=a; qq[j]=c;
  }
  #pragma unroll
  for (int o=32;o>0;o>>=1){
    #pragma unroll
    for (int j=0;j<COT;j++){ ss[j]+=__shfl_down(ss[j],o); qq[j]+=__shfl_down(qq[j],o); }
  }
  int lane = threadIdx.x & 63, wid = threadIdx.x >> 6;
  if (lane==0){
    #pragma unroll
    for (int j=0;j<COT;j++){ red[wid][j]=ss[j]; red[wid][COT+j]=qq[j]; }
  }
  __syncthreads();
  if (threadIdx.x < COT){
    int j = threadIdx.x;
    float a = red[0][j]+red[1][j]+red[2][j]+red[3][j];
    float c = red[0][COT+j]+red[1][COT+j]+red[2][COT+j]+red[3][COT+j];
    float* sp = &statOut[((size_t)b*Cout + co0 + j)*2];
    atomicAdd(sp, a); atomicAdd(sp+1, c);
  }
}

// ---------------- broadcast means back ----------------
__global__ void pool_bcast(float* __restrict__ out, const int* __restrict__ imap,
                           const float* __restrict__ sums, const float* __restrict__ cnts){
  const int P = 512*512;
  int b = blockIdx.y;
  __shared__ float lm[96];
  if (threadIdx.x < 96){
    int id = threadIdx.x/3;
    lm[threadIdx.x] = sums[b*96+threadIdx.x] / fmaxf(cnts[b*32+id], 1.0f);
  }
  __syncthreads();
  const int* mb = imap + (size_t)b*P;
  float* ob = out + (size_t)b*3*P;
  for (int p = blockIdx.x*blockDim.x + threadIdx.x; p < P; p += gridDim.x*blockDim.x){
    int id = mb[p];
    ob[p]     = lm[id*3+0];
    ob[P+p]   = lm[id*3+1];
    ob[2*P+p] = lm[id*3+2];
  }
}

static inline int cdiv(int a, int b){ return (a+b-1)/b; }

extern "C" void kernel_launch(void* const* d_in, const int* in_sizes, int n_in,
                              void* d_out, int out_size, void* d_ws, size_t ws_size,
                              hipStream_t stream) {
  const float* x    = (const float*)d_in[0];
  const int*   imap = (const int*)d_in[1];
  const float* w_in = (const float*)d_in[2];
  const float* b_in = (const float*)d_in[3];
  const float *wd[4], *bd[4], *wu[4], *bu[4];
  for (int i=0;i<4;i++){ wd[i]=(const float*)d_in[4+2*i];  bd[i]=(const float*)d_in[5+2*i]; }
  for (int i=0;i<4;i++){ wu[i]=(const float*)d_in[12+2*i]; bu[i]=(const float*)d_in[13+2*i]; }
  const float* w_out = (const float*)d_in[20];
  const float* b_out = (const float*)d_in[21];
  float* out = (float*)d_out;

  char* ws = (char*)d_ws;
  float* A     = (float*)ws;
  float* Bb    = (float*)(ws + (size_t)134217728);
  float* stats = (float*)(ws + (size_t)134217728 + (size_t)67108864);
  float* stLin = stats;          // 8*16*2  = 256
  float* std0  = stLin + 256;    // 8*32*2  = 512
  float* std1  = std0  + 512;    // 8*64*2  = 1024
  float* std2  = std1  + 1024;   // 8*128*2 = 2048
  float* std3  = std2  + 2048;   // 8*256*2 = 4096
  float* stu0  = std3  + 4096;   // 8*128*2 = 2048
  float* stu1  = stu0  + 2048;   // 8*64*2  = 1024
  float* stu2  = stu1  + 1024;   // 8*32*2  = 512
  float* stu3  = stu2  + 512;    // 8*16*2  = 256
  float* sums  = stu3  + 256;    // [8][32][3] = 768
  float* cnts  = sums  + 768;    // [8][32]    = 256
  hipMemsetAsync(stats, 0, (size_t)(11776 + 1024)*sizeof(float), stream);

  // conv_in: 3 -> 16 @ 512x512 (R23: T14 split)
  conv7_in_t<<<2048, 256, 0, stream>>>(x, w_in, b_in, A, stLin);

  // down path: wide 64x16 tiles (R21) + XCD-local decomposition (R22); d3 -> R20 kernel
  conv3s2_w64<16,8><<<2048, 256, 0, stream>>>(A,  wd[0], bd[0], Bb, 512, 512, stLin, std0);
  conv3s2_w64<32,8><<<1024, 256, 0, stream>>>(Bb, wd[1], bd[1], A,  256, 256, std0, std1);
  conv3s2_w64<64,4><<<1024, 256, 0, stream>>>(A,  wd[2], bd[2], Bb, 128, 128, std1, std2);
  conv3s2_lds<128,4><<<1024, 256, 0, stream>>>(Bb, wd[3], bd[3], A,  64,  64, std2, std3);

  // up path: LDS-staged + XCD-local decomposition (R22)
  tconv3_lds<256,2><<<1024, 256, 0, stream>>>(A,  wu[0], bu[0], Bb, 32, 32, std3, stu0);
  tconv3_lds<128,4><<<1024, 256, 0, stream>>>(Bb, wu[1], bu[1], A,  64, 64, stu0, stu1);
  tconv3_lds<64,4><<<2048, 256, 0, stream>>>(A,  wu[2], bu[2], Bb, 128, 128, stu1, stu2);
  tconv3_lds<32,4><<<4096, 256, 0, stream>>>(Bb, wu[3], bu[3], A,  256, 256, stu2, stu3);

  // conv_out: 16 -> 3 @ 512x512 + tanh + fused scatter-sum pooling (R19 + R23 T14 split)
  conv7_out_t<<<1024, 256, 0, stream>>>(A, w_out, b_out, out, stu3, imap, sums, cnts);

  // broadcast means back
  pool_bcast<<<dim3(128,BATCH),256,0,stream>>>(out, imap, sums, cnts);
}

// Round 9
// 1699.695 us; speedup vs baseline: 1.6168x; 1.6168x over previous
//
#include <hip/hip_runtime.h>
#include <math.h>
#include <type_traits>

#define BATCH 8
#define EPS 1e-5f

__device__ __forceinline__ int refl(int p, int n){ return p<0 ? -p : (p>=n ? 2*n-2-p : p); }

// stat layout per layer: stat[(b*C + c)*2] = sum, +1 = sumsq (atomic-accumulated)

// ---------------- conv_in: 3->16, 7x7, reflect pad 3, 512x512 ----------------
// R24: reverted to pre-R23 form (R23's T14 register-hold split spilled: VGPR 256, 4.2GB scratch).
__global__ __launch_bounds__(256) void conv7_in_t(const float* __restrict__ in,
    const float* __restrict__ w, const float* __restrict__ bias, float* __restrict__ out,
    float* __restrict__ statOut){
  const int H=512, W=512;
  __shared__ __align__(16) float wsm[3*49*16];
  __shared__ float bsm[16];
  __shared__ __align__(16) float tile[10][264];
  __shared__ float red[4][32];
  for (int t=threadIdx.x; t<2352; t+=256){
    int j = t & 15; int r = t >> 4;
    wsm[t] = w[j*147 + r];
  }
  if (threadIdx.x < 16) bsm[threadIdx.x] = bias[threadIdx.x];

  int bid = blockIdx.x;
  int b  = bid >> 8;
  int yt = (bid >> 1) & 127;  int y0 = yt*4;
  int xh = bid & 1;           int xbase = xh*256;
  int xq = threadIdx.x & 63;  int ty = threadIdx.x >> 6;
  int x0 = xq*4;              int y  = y0 + ty;

  int gy[10];
  #pragma unroll
  for (int r=0;r<10;r++) gy[r] = refl(y0-3+r, H);

  __syncthreads();
  float acc[16][4];
  #pragma unroll
  for (int j=0;j<16;j++){ float bv=bsm[j];
    #pragma unroll
    for (int p=0;p<4;p++) acc[j][p]=bv; }

  const float* inb = in + (size_t)b*3*H*W;
  for (int ci=0; ci<3; ++ci){
    const float* ipc = inb + (size_t)ci*H*W;
    for (int u=threadIdx.x; u<700; u+=256){
      if (u < 640){
        int r = u >> 6, k = u & 63;
        float4 v = *(const float4*)(ipc + (size_t)gy[r]*W + xbase + 4*k);
        *(float4*)&tile[r][4*k+4] = v;
      } else {
        int u2 = u - 640;
        int r = u2 / 6, h = u2 % 6;
        int L = (h<3) ? (1+h) : (257+h);
        int g = xbase + ((h<3) ? (h-3) : (253+h));
        tile[r][L] = ipc[(size_t)gy[r]*W + refl(g, W)];
      }
    }
    __syncthreads();
    #pragma unroll
    for (int ky=0; ky<7; ++ky){
      const float* tr = &tile[ty+ky][x0];
      float4 A  = *(const float4*)(tr);
      float4 Bv = *(const float4*)(tr+4);
      float4 Cv = *(const float4*)(tr+8);
      float rv[10] = {A.y,A.z,A.w,Bv.x,Bv.y,Bv.z,Bv.w,Cv.x,Cv.y,Cv.z};
      #pragma unroll
      for (int kx=0; kx<7; ++kx){
        const float4* wp = (const float4*)&wsm[(ci*49+ky*7+kx)*16];
        float4 w0=wp[0], w1=wp[1], w2=wp[2], w3=wp[3];
        float wv[16] = {w0.x,w0.y,w0.z,w0.w, w1.x,w1.y,w1.z,w1.w,
                        w2.x,w2.y,w2.z,w2.w, w3.x,w3.y,w3.z,w3.w};
        #pragma unroll
        for (int p=0;p<4;p++){
          float iv = rv[kx+p];
          #pragma unroll
          for (int j=0;j<16;j++) acc[j][p] = fmaf(iv, wv[j], acc[j][p]);
        }
      }
    }
    __syncthreads();
  }

  float* ob = out + ((size_t)(b*16)*H + y)*W + xbase + x0;
  #pragma unroll
  for (int j=0;j<16;j++){
    float4 v = {acc[j][0],acc[j][1],acc[j][2],acc[j][3]};
    *(float4*)(ob + (size_t)j*H*W) = v;
  }
  float ss[16], qq[16];
  #pragma unroll
  for (int j=0;j<16;j++){
    float a=0.f,c=0.f;
    #pragma unroll
    for (int p=0;p<4;p++){ a+=acc[j][p]; c=fmaf(acc[j][p],acc[j][p],c); }
    ss[j]=a; qq[j]=c;
  }
  #pragma unroll
  for (int o=32;o>0;o>>=1){
    #pragma unroll
    for (int j=0;j<16;j++){ ss[j]+=__shfl_down(ss[j],o); qq[j]+=__shfl_down(qq[j],o); }
  }
  int lane = threadIdx.x & 63, wid = threadIdx.x >> 6;
  if (lane==0){
    #pragma unroll
    for (int j=0;j<16;j++){ red[wid][j]=ss[j]; red[wid][16+j]=qq[j]; }
  }
  __syncthreads();
  if (threadIdx.x < 16){
    int j = threadIdx.x;
    float a = red[0][j]+red[1][j]+red[2][j]+red[3][j];
    float c = red[0][16+j]+red[1][16+j]+red[2][16+j]+red[3][16+j];
    float* sp = &statOut[((size_t)b*16 + j)*2];
    atomicAdd(sp, a); atomicAdd(sp+1, c);
  }
}

// ---------------- conv_out: 16->3, 7x7 reflect, tanh; normalizes input ----------------
// R24: 128-col tiles -> grid 2048 (8 blocks/CU, occupancy 16->~24-32 waves/CU).
// Block = 8 out rows x 128 px; 1 row x 4 px per thread. Tile 14x136 (7.6KB).
// No register-hold split (R23 spill lesson); latency hidden by block-level TLP.
// Per-output FMA chain (ci->ky->kx->p->j, s_load weights) identical to R19.
__global__ __launch_bounds__(256) void conv7_out_t(const float* __restrict__ in,
    const float* __restrict__ w, const float* __restrict__ bias, float* __restrict__ out,
    const float* __restrict__ statIn, const int* __restrict__ imap,
    float* __restrict__ sums, float* __restrict__ cnts){
  const int H=512, W=512;
  __shared__ float msm[16], ism[16];
  __shared__ __align__(16) float tile[14][136];
  __shared__ float ls[96];
  __shared__ float lc[32];
  if (threadIdx.x < 96) ls[threadIdx.x] = 0.f;
  if (threadIdx.x >= 96 && threadIdx.x < 128) lc[threadIdx.x-96] = 0.f;
  if (threadIdx.x < 16){
    const float invHW = 1.f/(512.f*512.f);
    float s  = statIn[((size_t)blockIdx.x>>8)*32 + threadIdx.x*2];
    float s2 = statIn[((size_t)blockIdx.x>>8)*32 + threadIdx.x*2+1];
    float m = s*invHW;
    float v = fmaxf(s2*invHW - m*m, 0.f);
    msm[threadIdx.x] = m; ism[threadIdx.x] = rsqrtf(v + EPS);
  }

  int bid = blockIdx.x;
  int b  = bid >> 8;                  // 2048 = 8b * 64yt * 4xh
  int yt = (bid >> 2) & 63;   int y0 = yt*8;
  int xh = bid & 3;           int xbase = xh*128;
  int xq = threadIdx.x & 31;  int row = threadIdx.x >> 5;   // 8 rows, 1/thread
  int x0 = xq*4;
  int y  = y0 + row;

  int gy[14];
  #pragma unroll
  for (int r=0;r<14;r++) gy[r] = refl(y0-3+r, H);

  __syncthreads();            // msm/ism, ls/lc visible

  float acc[3][4];
  #pragma unroll
  for (int j=0;j<3;j++){ float bv = bias[j];
    #pragma unroll
    for (int p=0;p<4;p++) acc[j][p]=bv; }

  const float* inb = in + (size_t)b*16*H*W;
  for (int ci=0; ci<16; ++ci){
    const float* ipc = inb + (size_t)ci*H*W;
    float m = msm[ci], is = ism[ci];
    // ---- stage 14 rows x 136 cols (128 data + 3+3 halo), normalize once ----
    #pragma unroll
    for (int q=0;q<3;q++){
      int u = threadIdx.x + q*256;
      if (u < 448){
        int r = u >> 5, k = u & 31;
        float4 v = *(const float4*)(ipc + (size_t)gy[r]*W + xbase + 4*k);
        v.x = fmaxf((v.x-m)*is, 0.f);
        v.y = fmaxf((v.y-m)*is, 0.f);
        v.z = fmaxf((v.z-m)*is, 0.f);
        v.w = fmaxf((v.w-m)*is, 0.f);
        *(float4*)&tile[r][4*k+4] = v;
      } else if (u < 532){
        int u2 = u - 448;
        int r = u2 / 6, h = u2 % 6;
        int L = (h<3) ? (1+h) : (129+h);
        int g = xbase + ((h<3) ? (h-3) : (125+h));
        float v = ipc[(size_t)gy[r]*W + refl(g, W)];
        tile[r][L] = fmaxf((v-m)*is, 0.f);
      }
    }
    __syncthreads();
    // ---- 7 ky taps for this thread's single row ----
    #pragma unroll
    for (int ky=0; ky<7; ++ky){
      const float* tr = &tile[row+ky][x0];
      float4 A  = *(const float4*)(tr);
      float4 Bv = *(const float4*)(tr+4);
      float4 Cv = *(const float4*)(tr+8);
      float rv[10] = {A.y,A.z,A.w,Bv.x,Bv.y,Bv.z,Bv.w,Cv.x,Cv.y,Cv.z};
      float wk[21];
      #pragma unroll
      for (int j=0;j<3;j++){
        const float* wj = w + j*784 + ci*49 + ky*7;   // uniform -> s_load
        #pragma unroll
        for (int kx=0;kx<7;kx++) wk[kx*3+j] = wj[kx];
      }
      #pragma unroll
      for (int kx=0;kx<7;kx++){
        float w0=wk[kx*3], w1=wk[kx*3+1], w2=wk[kx*3+2];
        #pragma unroll
        for (int p=0;p<4;p++){
          float iv = rv[kx+p];
          acc[0][p] = fmaf(iv, w0, acc[0][p]);
          acc[1][p] = fmaf(iv, w1, acc[1][p]);
          acc[2][p] = fmaf(iv, w2, acc[2][p]);
        }
      }
    }
    __syncthreads();
  }

  // tanh + store
  #pragma unroll
  for (int j=0;j<3;j++)
    #pragma unroll
    for (int p=0;p<4;p++) acc[j][p] = tanhf(acc[j][p]);

  float* ob = out + ((size_t)(b*3)*H + y)*W + xbase + x0;
  #pragma unroll
  for (int j=0;j<3;j++){
    float4 v0 = {acc[j][0],acc[j][1],acc[j][2],acc[j][3]};
    *(float4*)(ob + (size_t)j*H*W) = v0;
  }

  // ---- fused scatter-sum pooling epilogue ----
  const int* mb = imap + ((size_t)b*H + y)*W + xbase + x0;
  int4 i0 = *(const int4*)(mb);
  int im[4] = {i0.x,i0.y,i0.z,i0.w};
  #pragma unroll
  for (int p=0;p<4;p++){
    int id = im[p];
    atomicAdd(&ls[id*3+0], acc[0][p]);
    atomicAdd(&ls[id*3+1], acc[1][p]);
    atomicAdd(&ls[id*3+2], acc[2][p]);
    atomicAdd(&lc[id], 1.0f);
  }
  __syncthreads();
  if (threadIdx.x < 96) atomicAdd(&sums[b*96+threadIdx.x], ls[threadIdx.x]);
  if (threadIdx.x >= 96 && threadIdx.x < 128) atomicAdd(&cnts[b*32+threadIdx.x-96], lc[threadIdx.x-96]);
}

// ---------------- 3x3 stride-2 conv, WIDE 64x16 tile, 4 cols/thread (R21) ----------------
// R22: tile-index INNERMOST in bid (cgi outermost). All CG blocks sharing an input slab
// get bid = tile (mod NT), NT % 8 == 0 -> same XCD -> slab fetched from HBM once, rest L2.
template<int CIN, int COT>
__global__ __launch_bounds__(256,4) void conv3s2_w64(const float* __restrict__ in,
    const float* __restrict__ w, const float* __restrict__ bias, float* __restrict__ out,
    int Hin, int Win, const float* __restrict__ statIn, float* __restrict__ statOut){
  const int Cout = 2*CIN;
  const int TSTR = 136, ODD = 68;        // even[0..63], odd[68..132]
  __shared__ float msm[CIN], ism[CIN];
  __shared__ __align__(16) float tile[2][33*TSTR];   // 35.9 KB
  __shared__ float red[4][2*COT];
  int Hout = Hin>>1, Wout = Win>>1;
  int xtn = Wout>>6, ytn = Hout>>4;
  int NT = BATCH*xtn*ytn;                // multiple of 8
  int bid = blockIdx.x;
  int t = bid % NT; int cgi = bid / NT;  // R22: tile innermost -> XCD locality
  int xt  = t % xtn;  t /= xtn;
  int yt  = t % ytn;  int b = t / ytn;
  int co0 = cgi*COT;
  int X0 = xt<<6, Y0 = yt<<4;
  int IY0 = 2*Y0-1, GX = X0<<1;
  {
    float invHW = 1.f/(float)(Hin*Win);
    for (int t2=threadIdx.x; t2<CIN; t2+=256){
      float s  = statIn[((size_t)b*CIN + t2)*2];
      float s2 = statIn[((size_t)b*CIN + t2)*2+1];
      float m = s*invHW;
      float v = fmaxf(s2*invHW - m*m, 0.f);
      msm[t2] = m; ism[t2] = rsqrtf(v + EPS);
    }
  }
  __syncthreads();
  const float* inb = in + (size_t)b*CIN*Hin*Win;
  int xx = threadIdx.x & 15, ys = threadIdx.x >> 4;

  float4 vv[5];
  auto ld = [&](int ci){
    const float* ip = inb + (size_t)ci*Hin*Win;
    float m = msm[ci], is = ism[ci];
    #pragma unroll
    for (int q=0;q<5;q++){
      int u = threadIdx.x + q*256;
      if (u < 1089){
        int r = u/33, k = u - r*33;
        int iy = IY0 + r;
        bool okY = (unsigned)iy < (unsigned)Hin;
        if (k < 32){
          float4 v = {0.f,0.f,0.f,0.f};
          if (okY){
            v = *(const float4*)(ip + (size_t)iy*Win + GX + 4*k);
            v.x = fmaxf((v.x-m)*is, 0.f);
            v.y = fmaxf((v.y-m)*is, 0.f);
            v.z = fmaxf((v.z-m)*is, 0.f);
            v.w = fmaxf((v.w-m)*is, 0.f);
          }
          vv[q] = v;
        } else {
          float hv = 0.f;
          if (okY && X0 > 0) hv = fmaxf((ip[(size_t)iy*Win + GX-1]-m)*is, 0.f);
          vv[q].x = hv;
        }
      }
    }
  };
  auto st = [&](int buf){
    float* tb = tile[buf];
    #pragma unroll
    for (int q=0;q<5;q++){
      int u = threadIdx.x + q*256;
      if (u < 1089){
        int r = u/33, k = u - r*33;
        float* row = tb + r*TSTR;
        if (k < 32){
          float4 v = vv[q];
          float2 e = {v.x, v.z};
          *(float2*)(row + 2*k) = e;
          row[ODD + 2*k+1] = v.y;
          row[ODD + 2*k+2] = v.w;
        } else {
          row[ODD] = vv[q].x;
        }
      }
    }
  };

  float acc[COT][4];
  #pragma unroll
  for (int j=0;j<COT;j++){ float bv = bias[co0+j];
    #pragma unroll
    for (int p=0;p<4;p++) acc[j][p]=bv; }

  ld(0); st(0);
  for (int ci=0; ci<CIN; ++ci){
    __syncthreads();
    if (ci+1 < CIN) ld(ci+1);
    {
      const float* tb = tile[ci&1];
      float ev[3][4], od[3][5];
      #pragma unroll
      for (int ky=0;ky<3;ky++){
        const float* rowp = tb + (2*ys+ky)*TSTR;
        float4 e4 = *(const float4*)(rowp + 4*xx);
        float4 o4 = *(const float4*)(rowp + ODD + 4*xx);
        float o1  = rowp[ODD + 4*xx + 4];
        ev[ky][0]=e4.x; ev[ky][1]=e4.y; ev[ky][2]=e4.z; ev[ky][3]=e4.w;
        od[ky][0]=o4.x; od[ky][1]=o4.y; od[ky][2]=o4.z; od[ky][3]=o4.w; od[ky][4]=o1;
      }
      #pragma unroll
      for (int j=0;j<COT;j++){
        const float* wj = w + ((size_t)(co0+j)*CIN + ci)*9;   // uniform -> s_load
        float wk[9];
        #pragma unroll
        for (int k=0;k<9;k++) wk[k] = wj[k];
        #pragma unroll
        for (int p=0;p<4;p++){
          #pragma unroll
          for (int ky=0;ky<3;ky++){
            acc[j][p] = fmaf(od[ky][p],   wk[ky*3+0], acc[j][p]);
            acc[j][p] = fmaf(ev[ky][p],   wk[ky*3+1], acc[j][p]);
            acc[j][p] = fmaf(od[ky][p+1], wk[ky*3+2], acc[j][p]);
          }
        }
      }
    }
    if (ci+1 < CIN) st((ci+1)&1);
  }

  float* ob = out + ((size_t)b*Cout + co0)*Hout*Wout + (size_t)(Y0+ys)*Wout + X0 + 4*xx;
  #pragma unroll
  for (int j=0;j<COT;j++){
    float4 v = {acc[j][0],acc[j][1],acc[j][2],acc[j][3]};
    *(float4*)(ob + (size_t)j*Hout*Wout) = v;
  }
  // ---- stats ----
  float ss[COT], qq[COT];
  #pragma unroll
  for (int j=0;j<COT;j++){
    float a=0.f,c=0.f;
    #pragma unroll
    for (int p=0;p<4;p++){ a+=acc[j][p]; c=fmaf(acc[j][p],acc[j][p],c); }
    ss[j]=a; qq[j]=c;
  }
  #pragma unroll
  for (int o=32;o>0;o>>=1){
    #pragma unroll
    for (int j=0;j<COT;j++){ ss[j]+=__shfl_down(ss[j],o); qq[j]+=__shfl_down(qq[j],o); }
  }
  int lane = threadIdx.x & 63, wid = threadIdx.x >> 6;
  if (lane==0){
    #pragma unroll
    for (int j=0;j<COT;j++){ red[wid][j]=ss[j]; red[wid][COT+j]=qq[j]; }
  }
  __syncthreads();
  if (threadIdx.x < COT){
    int j = threadIdx.x;
    float a = red[0][j]+red[1][j]+red[2][j]+red[3][j];
    float c = red[0][COT+j]+red[1][COT+j]+red[2][COT+j]+red[3][COT+j];
    float* sp = &statOut[((size_t)b*Cout + co0 + j)*2];
    atomicAdd(sp, a); atomicAdd(sp+1, c);
  }
}

// ---------------- 3x3 stride-2 conv, 32x16 tile (R20; d3). R22 XCD-local decomposition ----------------
template<int CIN, int COT>
__global__ __launch_bounds__(256,4) void conv3s2_lds(const float* __restrict__ in,
    const float* __restrict__ w, const float* __restrict__ bias, float* __restrict__ out,
    int Hin, int Win, const float* __restrict__ statIn, float* __restrict__ statOut){
  const int Cout = 2*CIN;
  const int TSTR = 72;
  __shared__ float msm[CIN], ism[CIN];
  __shared__ __align__(16) float tile[2][33*TSTR];
  __shared__ float red[4][2*COT];
  int Hout = Hin>>1, Wout = Win>>1;
  int xtn = Wout>>5, ytn = Hout>>4;
  int NT = BATCH*xtn*ytn;                // multiple of 8
  int bid = blockIdx.x;
  int t = bid % NT; int cgi = bid / NT;  // R22: tile innermost -> XCD locality
  int xt  = t % xtn;  t /= xtn;
  int yt  = t % ytn;  int b = t / ytn;
  int co0 = cgi*COT;
  int X0 = xt<<5, Y0 = yt<<4;
  int IY0 = 2*Y0-1, GX = X0<<1;
  {
    float invHW = 1.f/(float)(Hin*Win);
    for (int t2=threadIdx.x; t2<CIN; t2+=256){
      float s  = statIn[((size_t)b*CIN + t2)*2];
      float s2 = statIn[((size_t)b*CIN + t2)*2+1];
      float m = s*invHW;
      float v = fmaxf(s2*invHW - m*m, 0.f);
      msm[t2] = m; ism[t2] = rsqrtf(v + EPS);
    }
  }
  __syncthreads();
  const float* inb = in + (size_t)b*CIN*Hin*Win;
  int xx = threadIdx.x & 31, ys = threadIdx.x >> 5;

  float4 vv[3]; float hh[3];
  auto ld = [&](int ci){
    const float* ip = inb + (size_t)ci*Hin*Win;
    float m = msm[ci], is = ism[ci];
    #pragma unroll
    for (int q=0;q<3;q++){
      int u = threadIdx.x + q*256;
      if (u < 561){
        int r = u/17, k = u - r*17;
        int iy = IY0 + r;
        bool okY = (unsigned)iy < (unsigned)Hin;
        if (k < 16){
          float4 v = {0.f,0.f,0.f,0.f};
          if (okY){
            v = *(const float4*)(ip + (size_t)iy*Win + GX + 4*k);
            v.x = fmaxf((v.x-m)*is, 0.f);
            v.y = fmaxf((v.y-m)*is, 0.f);
            v.z = fmaxf((v.z-m)*is, 0.f);
            v.w = fmaxf((v.w-m)*is, 0.f);
          }
          vv[q] = v;
        } else {
          float hv = 0.f;
          if (okY && X0 > 0) hv = fmaxf((ip[(size_t)iy*Win + GX-1]-m)*is, 0.f);
          hh[q] = hv;
        }
      }
    }
  };
  auto st = [&](int buf){
    float* tb = tile[buf];
    #pragma unroll
    for (int q=0;q<3;q++){
      int u = threadIdx.x + q*256;
      if (u < 561){
        int r = u/17, k = u - r*17;
        float* row = tb + r*TSTR;
        if (k < 16){
          float4 v = vv[q];
          row[2*k]        = v.x;
          row[2*k+1]      = v.z;
          row[36+2*k+1]   = v.y;
          row[36+2*k+2]   = v.w;
        } else {
          row[36] = hh[q];
        }
      }
    }
  };

  float acc[COT][2];
  #pragma unroll
  for (int j=0;j<COT;j++){ float bv = bias[co0+j]; acc[j][0]=bv; acc[j][1]=bv; }

  ld(0); st(0);
  for (int ci=0; ci<CIN; ++ci){
    __syncthreads();
    if (ci+1 < CIN) ld(ci+1);
    {
      const float* tb = tile[ci&1];
      float rv[2][3][3];
      #pragma unroll
      for (int g=0;g<2;g++){
        int rb = (ys + (g<<3))<<1;
        #pragma unroll
        for (int ky=0;ky<3;ky++){
          const float* er = tb + (rb+ky)*TSTR;
          const float* od = er + 36;
          rv[g][ky][0]=od[xx]; rv[g][ky][1]=er[xx]; rv[g][ky][2]=od[xx+1];
        }
      }
      #pragma unroll
      for (int j=0;j<COT;j++){
        const float* wj = w + ((size_t)(co0+j)*CIN + ci)*9;   // uniform -> s_load
        float wk[9];
        #pragma unroll
        for (int k=0;k<9;k++) wk[k] = wj[k];
        #pragma unroll
        for (int g=0;g<2;g++)
          #pragma unroll
          for (int ky=0;ky<3;ky++)
            #pragma unroll
            for (int kx=0;kx<3;kx++)
              acc[j][g] = fmaf(rv[g][ky][kx], wk[ky*3+kx], acc[j][g]);
      }
    }
    if (ci+1 < CIN) st((ci+1)&1);
  }

  float* ob = out + ((size_t)b*Cout + co0)*Hout*Wout;
  #pragma unroll
  for (int j=0;j<COT;j++)
    #pragma unroll
    for (int g=0;g<2;g++){
      int oy = ys + (g<<3);
      ob[(size_t)j*Hout*Wout + (Y0+oy)*Wout + X0 + xx] = acc[j][g];
    }
  // ---- stats ----
  float ss[COT], qq[COT];
  #pragma unroll
  for (int j=0;j<COT;j++){
    float a = acc[j][0] + acc[j][1];
    float c = fmaf(acc[j][0],acc[j][0], acc[j][1]*acc[j][1]);
    ss[j]=a; qq[j]=c;
  }
  #pragma unroll
  for (int o=32;o>0;o>>=1){
    #pragma unroll
    for (int j=0;j<COT;j++){ ss[j]+=__shfl_down(ss[j],o); qq[j]+=__shfl_down(qq[j],o); }
  }
  int lane = threadIdx.x & 63, wid = threadIdx.x >> 6;
  if (lane==0){
    #pragma unroll
    for (int j=0;j<COT;j++){ red[wid][j]=ss[j]; red[wid][COT+j]=qq[j]; }
  }
  __syncthreads();
  if (threadIdx.x < COT){
    int j = threadIdx.x;
    float a = red[0][j]+red[1][j]+red[2][j]+red[3][j];
    float c = red[0][COT+j]+red[1][COT+j]+red[2][COT+j]+red[3][COT+j];
    float* sp = &statOut[((size_t)b*Cout + co0 + j)*2];
    atomicAdd(sp, a); atomicAdd(sp+1, c);
  }
}

// ---------------- tconv k=3 s=2 p=1 op=1; LDS-staged. R22 XCD-local decomposition ----------------
template<int CIN, int COT>
__global__ __launch_bounds__(256,4) void tconv3_lds(const float* __restrict__ in,
    const float* __restrict__ w, const float* __restrict__ bias, float* __restrict__ out,
    int Hin, int Win, const float* __restrict__ statIn, float* __restrict__ statOut){
  const int Cout = CIN/2;
  const int TSTR = 36;
  __shared__ float msm[CIN], ism[CIN];
  __shared__ __align__(16) float tile[2][17*TSTR];
  __shared__ float red[4][2*COT];
  int Hout = Hin<<1, Wout = Win<<1;
  int xtn = Win>>5, ytn = Hin>>4;
  int NT = BATCH*xtn*ytn;                // multiple of 8
  int bid = blockIdx.x;
  int t = bid % NT; int cgi = bid / NT;  // R22: tile innermost -> XCD locality
  int xt  = t % xtn;  t /= xtn;
  int yt  = t % ytn;  int b = t / ytn;
  int co0 = cgi*COT;
  int X0 = xt<<5, Y0 = yt<<4;
  {
    float invHW = 1.f/(float)(Hin*Win);
    for (int t2=threadIdx.x; t2<CIN; t2+=256){
      float s  = statIn[((size_t)b*CIN + t2)*2];
      float s2 = statIn[((size_t)b*CIN + t2)*2+1];
      float m = s*invHW;
      float v = fmaxf(s2*invHW - m*m, 0.f);
      msm[t2] = m; ism[t2] = rsqrtf(v + EPS);
    }
  }
  __syncthreads();
  const float* inb = in + (size_t)b*CIN*Hin*Win;
  int xx = threadIdx.x & 31, ys = threadIdx.x >> 5;

  float4 sv; float sh;
  auto ld = [&](int ci){
    const float* ip = inb + (size_t)ci*Hin*Win;
    float m = msm[ci], is = ism[ci];
    int u = threadIdx.x;
    if (u < 153){
      int r = u/9, k = u - r*9;
      int iy = Y0 + r;
      bool okY = iy < Hin;
      if (k < 8){
        float4 v = {0.f,0.f,0.f,0.f};
        if (okY){
          v = *(const float4*)(ip + (size_t)iy*Win + X0 + 4*k);
          v.x = fmaxf((v.x-m)*is, 0.f);
          v.y = fmaxf((v.y-m)*is, 0.f);
          v.z = fmaxf((v.z-m)*is, 0.f);
          v.w = fmaxf((v.w-m)*is, 0.f);
        }
        sv = v;
      } else {
        float hv = 0.f;
        int xc = X0 + 32;
        if (okY && xc < Win) hv = fmaxf((ip[(size_t)iy*Win + xc]-m)*is, 0.f);
        sh = hv;
      }
    }
  };
  auto st = [&](int buf){
    int u = threadIdx.x;
    if (u < 153){
      int r = u/9, k = u - r*9;
      if (k < 8) *(float4*)(tile[buf] + r*TSTR + 4*k) = sv;
      else tile[buf][r*TSTR + 32] = sh;
    }
  };

  float acc[COT][2][2][2];
  #pragma unroll
  for (int j=0;j<COT;j++){ float bv = bias[co0+j];
    #pragma unroll
    for (int g=0;g<2;g++)
      #pragma unroll
      for (int oy=0;oy<2;oy++){ acc[j][g][oy][0]=bv; acc[j][g][oy][1]=bv; } }

  ld(0); st(0);
  for (int ci=0; ci<CIN; ++ci){
    __syncthreads();
    if (ci+1 < CIN) ld(ci+1);
    {
      const float* tb = tile[ci&1];
      float v[2][2][2];
      #pragma unroll
      for (int g=0;g<2;g++){
        int rb = ys + (g<<3);
        const float* t0 = tb + rb*TSTR + xx;
        v[g][0][0]=t0[0]; v[g][0][1]=t0[1];
        v[g][1][0]=t0[TSTR]; v[g][1][1]=t0[TSTR+1];
      }
      #pragma unroll
      for (int j=0;j<COT;j++){
        const float* wj = w + ((size_t)ci*Cout + co0+j)*9;   // uniform -> s_load
        float wk[9];
        #pragma unroll
        for (int k=0;k<9;k++) wk[k] = wj[k];
        #pragma unroll
        for (int g=0;g<2;g++){
          float v00=v[g][0][0], v01=v[g][0][1], v10=v[g][1][0], v11=v[g][1][1];
          acc[j][g][0][0] = fmaf(v00, wk[4], acc[j][g][0][0]);
          acc[j][g][0][1] = fmaf(v00, wk[5], fmaf(v01, wk[3], acc[j][g][0][1]));
          acc[j][g][1][0] = fmaf(v00, wk[7], fmaf(v10, wk[1], acc[j][g][1][0]));
          acc[j][g][1][1] = fmaf(v00, wk[8], fmaf(v01, wk[6],
                             fmaf(v10, wk[2], fmaf(v11, wk[0], acc[j][g][1][1]))));
        }
      }
    }
    if (ci+1 < CIN) st((ci+1)&1);
  }

  float* ob = out + ((size_t)b*Cout + co0)*Hout*Wout;
  #pragma unroll
  for (int j=0;j<COT;j++)
    #pragma unroll
    for (int g=0;g<2;g++)
      #pragma unroll
      for (int oy=0;oy<2;oy++){
        int orow = 2*(Y0 + ys + (g<<3)) + oy;
        float2 v2 = {acc[j][g][oy][0], acc[j][g][oy][1]};
        *(float2*)(ob + (size_t)j*Hout*Wout + (size_t)orow*Wout + 2*(X0+xx)) = v2;
      }
  // ---- stats ----
  float ss[COT], qq[COT];
  #pragma unroll
  for (int j=0;j<COT;j++){
    float a=0.f,c=0.f;
    #pragma unroll
    for (int g=0;g<2;g++)
      #pragma unroll
      for (int oy=0;oy<2;oy++)
        #pragma unroll
        for (int ox=0;ox<2;ox++){ float u=acc[j][g][oy][ox]; a+=u; c=fmaf(u,u,c); }
    ss[j]=a; qq[j]=c;
  }
  #pragma unroll
  for (int o=32;o>0;o>>=1){
    #pragma unroll
    for (int j=0;j<COT;j++){ ss[j]+=__shfl_down(ss[j],o); qq[j]+=__shfl_down(qq[j],o); }
  }
  int lane = threadIdx.x & 63, wid = threadIdx.x >> 6;
  if (lane==0){
    #pragma unroll
    for (int j=0;j<COT;j++){ red[wid][j]=ss[j]; red[wid][COT+j]=qq[j]; }
  }
  __syncthreads();
  if (threadIdx.x < COT){
    int j = threadIdx.x;
    float a = red[0][j]+red[1][j]+red[2][j]+red[3][j];
    float c = red[0][COT+j]+red[1][COT+j]+red[2][COT+j]+red[3][COT+j];
    float* sp = &statOut[((size_t)b*Cout + co0 + j)*2];
    atomicAdd(sp, a); atomicAdd(sp+1, c);
  }
}

// ---------------- broadcast means back ----------------
__global__ void pool_bcast(float* __restrict__ out, const int* __restrict__ imap,
                           const float* __restrict__ sums, const float* __restrict__ cnts){
  const int P = 512*512;
  int b = blockIdx.y;
  __shared__ float lm[96];
  if (threadIdx.x < 96){
    int id = threadIdx.x/3;
    lm[threadIdx.x] = sums[b*96+threadIdx.x] / fmaxf(cnts[b*32+id], 1.0f);
  }
  __syncthreads();
  const int* mb = imap + (size_t)b*P;
  float* ob = out + (size_t)b*3*P;
  for (int p = blockIdx.x*blockDim.x + threadIdx.x; p < P; p += gridDim.x*blockDim.x){
    int id = mb[p];
    ob[p]     = lm[id*3+0];
    ob[P+p]   = lm[id*3+1];
    ob[2*P+p] = lm[id*3+2];
  }
}

static inline int cdiv(int a, int b){ return (a+b-1)/b; }

extern "C" void kernel_launch(void* const* d_in, const int* in_sizes, int n_in,
                              void* d_out, int out_size, void* d_ws, size_t ws_size,
                              hipStream_t stream) {
  const float* x    = (const float*)d_in[0];
  const int*   imap = (const int*)d_in[1];
  const float* w_in = (const float*)d_in[2];
  const float* b_in = (const float*)d_in[3];
  const float *wd[4], *bd[4], *wu[4], *bu[4];
  for (int i=0;i<4;i++){ wd[i]=(const float*)d_in[4+2*i];  bd[i]=(const float*)d_in[5+2*i]; }
  for (int i=0;i<4;i++){ wu[i]=(const float*)d_in[12+2*i]; bu[i]=(const float*)d_in[13+2*i]; }
  const float* w_out = (const float*)d_in[20];
  const float* b_out = (const float*)d_in[21];
  float* out = (float*)d_out;

  char* ws = (char*)d_ws;
  float* A     = (float*)ws;
  float* Bb    = (float*)(ws + (size_t)134217728);
  float* stats = (float*)(ws + (size_t)134217728 + (size_t)67108864);
  float* stLin = stats;          // 8*16*2  = 256
  float* std0  = stLin + 256;    // 8*32*2  = 512
  float* std1  = std0  + 512;    // 8*64*2  = 1024
  float* std2  = std1  + 1024;   // 8*128*2 = 2048
  float* std3  = std2  + 2048;   // 8*256*2 = 4096
  float* stu0  = std3  + 4096;   // 8*128*2 = 2048
  float* stu1  = stu0  + 2048;   // 8*64*2  = 1024
  float* stu2  = stu1  + 1024;   // 8*32*2  = 512
  float* stu3  = stu2  + 512;    // 8*16*2  = 256
  float* sums  = stu3  + 256;    // [8][32][3] = 768
  float* cnts  = sums  + 768;    // [8][32]    = 256
  hipMemsetAsync(stats, 0, (size_t)(11776 + 1024)*sizeof(float), stream);

  // conv_in: 3 -> 16 @ 512x512 (R24: reverted to pre-R23, no-spill version)
  conv7_in_t<<<2048, 256, 0, stream>>>(x, w_in, b_in, A, stLin);

  // down path: wide 64x16 tiles (R21) + XCD-local decomposition (R22); d3 -> R20 kernel
  conv3s2_w64<16,8><<<2048, 256, 0, stream>>>(A,  wd[0], bd[0], Bb, 512, 512, stLin, std0);
  conv3s2_w64<32,8><<<1024, 256, 0, stream>>>(Bb, wd[1], bd[1], A,  256, 256, std0, std1);
  conv3s2_w64<64,4><<<1024, 256, 0, stream>>>(A,  wd[2], bd[2], Bb, 128, 128, std1, std2);
  conv3s2_lds<128,4><<<1024, 256, 0, stream>>>(Bb, wd[3], bd[3], A,  64,  64, std2, std3);

  // up path: LDS-staged + XCD-local decomposition (R22)
  tconv3_lds<256,2><<<1024, 256, 0, stream>>>(A,  wu[0], bu[0], Bb, 32, 32, std3, stu0);
  tconv3_lds<128,4><<<1024, 256, 0, stream>>>(Bb, wu[1], bu[1], A,  64, 64, stu0, stu1);
  tconv3_lds<64,4><<<2048, 256, 0, stream>>>(A,  wu[2], bu[2], Bb, 128, 128, stu1, stu2);
  tconv3_lds<32,4><<<4096, 256, 0, stream>>>(Bb, wu[3], bu[3], A,  256, 256, stu2, stu3);

  // conv_out: 16 -> 3 @ 512x512 + tanh + fused scatter-sum pooling
  // (R24: 128-col tiles, grid 2048, occupancy-driven latency hiding)
  conv7_out_t<<<2048, 256, 0, stream>>>(A, w_out, b_out, out, stu3, imap, sums, cnts);

  // broadcast means back
  pool_bcast<<<dim3(128,BATCH),256,0,stream>>>(out, imap, sums, cnts);
}

// Round 10
// 1571.482 us; speedup vs baseline: 1.7487x; 1.0816x over previous
//
#include <hip/hip_runtime.h>
#include <math.h>
#include <type_traits>

#define BATCH 8
#define EPS 1e-5f

__device__ __forceinline__ int refl(int p, int n){ return p<0 ? -p : (p>=n ? 2*n-2-p : p); }

// stat layout per layer: stat[(b*C + c)*2] = sum, +1 = sumsq (atomic-accumulated)

// R25 block remap: same-tile blocks must be SAME-XCD **and dispatch-adjacent**.
// xcd = bid&7 (round-robin heuristic); per-XCD slot s = bid>>3; cgi inner, tile outer.
// R22 failed because cgi = bid/NT put same-tile blocks NT apart in time -> L2 evicted.

// ---------------- conv_in: 3->16, 7x7, reflect pad 3, 512x512 ----------------
__global__ __launch_bounds__(256) void conv7_in_t(const float* __restrict__ in,
    const float* __restrict__ w, const float* __restrict__ bias, float* __restrict__ out,
    float* __restrict__ statOut){
  const int H=512, W=512;
  __shared__ __align__(16) float wsm[3*49*16];
  __shared__ float bsm[16];
  __shared__ __align__(16) float tile[10][264];
  __shared__ float red[4][32];
  for (int t=threadIdx.x; t<2352; t+=256){
    int j = t & 15; int r = t >> 4;
    wsm[t] = w[j*147 + r];
  }
  if (threadIdx.x < 16) bsm[threadIdx.x] = bias[threadIdx.x];

  int bid = blockIdx.x;
  int b  = bid >> 8;
  int yt = (bid >> 1) & 127;  int y0 = yt*4;
  int xh = bid & 1;           int xbase = xh*256;
  int xq = threadIdx.x & 63;  int ty = threadIdx.x >> 6;
  int x0 = xq*4;              int y  = y0 + ty;

  int gy[10];
  #pragma unroll
  for (int r=0;r<10;r++) gy[r] = refl(y0-3+r, H);

  __syncthreads();
  float acc[16][4];
  #pragma unroll
  for (int j=0;j<16;j++){ float bv=bsm[j];
    #pragma unroll
    for (int p=0;p<4;p++) acc[j][p]=bv; }

  const float* inb = in + (size_t)b*3*H*W;
  for (int ci=0; ci<3; ++ci){
    const float* ipc = inb + (size_t)ci*H*W;
    for (int u=threadIdx.x; u<700; u+=256){
      if (u < 640){
        int r = u >> 6, k = u & 63;
        float4 v = *(const float4*)(ipc + (size_t)gy[r]*W + xbase + 4*k);
        *(float4*)&tile[r][4*k+4] = v;
      } else {
        int u2 = u - 640;
        int r = u2 / 6, h = u2 % 6;
        int L = (h<3) ? (1+h) : (257+h);
        int g = xbase + ((h<3) ? (h-3) : (253+h));
        tile[r][L] = ipc[(size_t)gy[r]*W + refl(g, W)];
      }
    }
    __syncthreads();
    #pragma unroll
    for (int ky=0; ky<7; ++ky){
      const float* tr = &tile[ty+ky][x0];
      float4 A  = *(const float4*)(tr);
      float4 Bv = *(const float4*)(tr+4);
      float4 Cv = *(const float4*)(tr+8);
      float rv[10] = {A.y,A.z,A.w,Bv.x,Bv.y,Bv.z,Bv.w,Cv.x,Cv.y,Cv.z};
      #pragma unroll
      for (int kx=0; kx<7; ++kx){
        const float4* wp = (const float4*)&wsm[(ci*49+ky*7+kx)*16];
        float4 w0=wp[0], w1=wp[1], w2=wp[2], w3=wp[3];
        float wv[16] = {w0.x,w0.y,w0.z,w0.w, w1.x,w1.y,w1.z,w1.w,
                        w2.x,w2.y,w2.z,w2.w, w3.x,w3.y,w3.z,w3.w};
        #pragma unroll
        for (int p=0;p<4;p++){
          float iv = rv[kx+p];
          #pragma unroll
          for (int j=0;j<16;j++) acc[j][p] = fmaf(iv, wv[j], acc[j][p]);
        }
      }
    }
    __syncthreads();
  }

  float* ob = out + ((size_t)(b*16)*H + y)*W + xbase + x0;
  #pragma unroll
  for (int j=0;j<16;j++){
    float4 v = {acc[j][0],acc[j][1],acc[j][2],acc[j][3]};
    *(float4*)(ob + (size_t)j*H*W) = v;
  }
  float ss[16], qq[16];
  #pragma unroll
  for (int j=0;j<16;j++){
    float a=0.f,c=0.f;
    #pragma unroll
    for (int p=0;p<4;p++){ a+=acc[j][p]; c=fmaf(acc[j][p],acc[j][p],c); }
    ss[j]=a; qq[j]=c;
  }
  #pragma unroll
  for (int o=32;o>0;o>>=1){
    #pragma unroll
    for (int j=0;j<16;j++){ ss[j]+=__shfl_down(ss[j],o); qq[j]+=__shfl_down(qq[j],o); }
  }
  int lane = threadIdx.x & 63, wid = threadIdx.x >> 6;
  if (lane==0){
    #pragma unroll
    for (int j=0;j<16;j++){ red[wid][j]=ss[j]; red[wid][16+j]=qq[j]; }
  }
  __syncthreads();
  if (threadIdx.x < 16){
    int j = threadIdx.x;
    float a = red[0][j]+red[1][j]+red[2][j]+red[3][j];
    float c = red[0][16+j]+red[1][16+j]+red[2][16+j]+red[3][16+j];
    float* sp = &statOut[((size_t)b*16 + j)*2];
    atomicAdd(sp, a); atomicAdd(sp+1, c);
  }
}

// ---------------- conv_out: 16->3, 7x7 reflect, tanh; normalizes input (R24) ----------------
__global__ __launch_bounds__(256) void conv7_out_t(const float* __restrict__ in,
    const float* __restrict__ w, const float* __restrict__ bias, float* __restrict__ out,
    const float* __restrict__ statIn, const int* __restrict__ imap,
    float* __restrict__ sums, float* __restrict__ cnts){
  const int H=512, W=512;
  __shared__ float msm[16], ism[16];
  __shared__ __align__(16) float tile[14][136];
  __shared__ float ls[96];
  __shared__ float lc[32];
  if (threadIdx.x < 96) ls[threadIdx.x] = 0.f;
  if (threadIdx.x >= 96 && threadIdx.x < 128) lc[threadIdx.x-96] = 0.f;
  if (threadIdx.x < 16){
    const float invHW = 1.f/(512.f*512.f);
    float s  = statIn[((size_t)blockIdx.x>>8)*32 + threadIdx.x*2];
    float s2 = statIn[((size_t)blockIdx.x>>8)*32 + threadIdx.x*2+1];
    float m = s*invHW;
    float v = fmaxf(s2*invHW - m*m, 0.f);
    msm[threadIdx.x] = m; ism[threadIdx.x] = rsqrtf(v + EPS);
  }

  int bid = blockIdx.x;
  int b  = bid >> 8;                  // 2048 = 8b * 64yt * 4xh
  int yt = (bid >> 2) & 63;   int y0 = yt*8;
  int xh = bid & 3;           int xbase = xh*128;
  int xq = threadIdx.x & 31;  int row = threadIdx.x >> 5;   // 8 rows, 1/thread
  int x0 = xq*4;
  int y  = y0 + row;

  int gy[14];
  #pragma unroll
  for (int r=0;r<14;r++) gy[r] = refl(y0-3+r, H);

  __syncthreads();            // msm/ism, ls/lc visible

  float acc[3][4];
  #pragma unroll
  for (int j=0;j<3;j++){ float bv = bias[j];
    #pragma unroll
    for (int p=0;p<4;p++) acc[j][p]=bv; }

  const float* inb = in + (size_t)b*16*H*W;
  for (int ci=0; ci<16; ++ci){
    const float* ipc = inb + (size_t)ci*H*W;
    float m = msm[ci], is = ism[ci];
    #pragma unroll
    for (int q=0;q<3;q++){
      int u = threadIdx.x + q*256;
      if (u < 448){
        int r = u >> 5, k = u & 31;
        float4 v = *(const float4*)(ipc + (size_t)gy[r]*W + xbase + 4*k);
        v.x = fmaxf((v.x-m)*is, 0.f);
        v.y = fmaxf((v.y-m)*is, 0.f);
        v.z = fmaxf((v.z-m)*is, 0.f);
        v.w = fmaxf((v.w-m)*is, 0.f);
        *(float4*)&tile[r][4*k+4] = v;
      } else if (u < 532){
        int u2 = u - 448;
        int r = u2 / 6, h = u2 % 6;
        int L = (h<3) ? (1+h) : (129+h);
        int g = xbase + ((h<3) ? (h-3) : (125+h));
        float v = ipc[(size_t)gy[r]*W + refl(g, W)];
        tile[r][L] = fmaxf((v-m)*is, 0.f);
      }
    }
    __syncthreads();
    #pragma unroll
    for (int ky=0; ky<7; ++ky){
      const float* tr = &tile[row+ky][x0];
      float4 A  = *(const float4*)(tr);
      float4 Bv = *(const float4*)(tr+4);
      float4 Cv = *(const float4*)(tr+8);
      float rv[10] = {A.y,A.z,A.w,Bv.x,Bv.y,Bv.z,Bv.w,Cv.x,Cv.y,Cv.z};
      float wk[21];
      #pragma unroll
      for (int j=0;j<3;j++){
        const float* wj = w + j*784 + ci*49 + ky*7;   // uniform -> s_load
        #pragma unroll
        for (int kx=0;kx<7;kx++) wk[kx*3+j] = wj[kx];
      }
      #pragma unroll
      for (int kx=0;kx<7;kx++){
        float w0=wk[kx*3], w1=wk[kx*3+1], w2=wk[kx*3+2];
        #pragma unroll
        for (int p=0;p<4;p++){
          float iv = rv[kx+p];
          acc[0][p] = fmaf(iv, w0, acc[0][p]);
          acc[1][p] = fmaf(iv, w1, acc[1][p]);
          acc[2][p] = fmaf(iv, w2, acc[2][p]);
        }
      }
    }
    __syncthreads();
  }

  #pragma unroll
  for (int j=0;j<3;j++)
    #pragma unroll
    for (int p=0;p<4;p++) acc[j][p] = tanhf(acc[j][p]);

  float* ob = out + ((size_t)(b*3)*H + y)*W + xbase + x0;
  #pragma unroll
  for (int j=0;j<3;j++){
    float4 v0 = {acc[j][0],acc[j][1],acc[j][2],acc[j][3]};
    *(float4*)(ob + (size_t)j*H*W) = v0;
  }

  const int* mb = imap + ((size_t)b*H + y)*W + xbase + x0;
  int4 i0 = *(const int4*)(mb);
  int im[4] = {i0.x,i0.y,i0.z,i0.w};
  #pragma unroll
  for (int p=0;p<4;p++){
    int id = im[p];
    atomicAdd(&ls[id*3+0], acc[0][p]);
    atomicAdd(&ls[id*3+1], acc[1][p]);
    atomicAdd(&ls[id*3+2], acc[2][p]);
    atomicAdd(&lc[id], 1.0f);
  }
  __syncthreads();
  if (threadIdx.x < 96) atomicAdd(&sums[b*96+threadIdx.x], ls[threadIdx.x]);
  if (threadIdx.x >= 96 && threadIdx.x < 128) atomicAdd(&cnts[b*32+threadIdx.x-96], lc[threadIdx.x-96]);
}

// ---------------- 3x3 stride-2 conv, WIDE 64x16 tile, 4 cols/thread (R21+R25) ----------------
template<int CIN, int COT>
__global__ __launch_bounds__(256,4) void conv3s2_w64(const float* __restrict__ in,
    const float* __restrict__ w, const float* __restrict__ bias, float* __restrict__ out,
    int Hin, int Win, const float* __restrict__ statIn, float* __restrict__ statOut){
  const int Cout = 2*CIN;
  const int CG = Cout/COT;
  const int TSTR = 136, ODD = 68;        // even[0..63], odd[68..132]
  __shared__ float msm[CIN], ism[CIN];
  __shared__ __align__(16) float tile[2][33*TSTR];   // 35.9 KB
  __shared__ float red[4][2*COT];
  int Hout = Hin>>1, Wout = Win>>1;
  int xtn = Wout>>6, ytn = Hout>>4;
  int NT = BATCH*xtn*ytn;                // multiple of 8
  // R25: xcd-adjacent: same-tile blocks contiguous on one XCD
  int bid = blockIdx.x;
  int xcd = bid & 7; int s = bid >> 3;
  int cgi = s % CG;  int tq = s / CG;
  int t = xcd*(NT>>3) + tq;
  int xt  = t % xtn;  t /= xtn;
  int yt  = t % ytn;  int b = t / ytn;
  int co0 = cgi*COT;
  int X0 = xt<<6, Y0 = yt<<4;
  int IY0 = 2*Y0-1, GX = X0<<1;
  {
    float invHW = 1.f/(float)(Hin*Win);
    for (int t2=threadIdx.x; t2<CIN; t2+=256){
      float s0  = statIn[((size_t)b*CIN + t2)*2];
      float s2 = statIn[((size_t)b*CIN + t2)*2+1];
      float m = s0*invHW;
      float v = fmaxf(s2*invHW - m*m, 0.f);
      msm[t2] = m; ism[t2] = rsqrtf(v + EPS);
    }
  }
  __syncthreads();
  const float* inb = in + (size_t)b*CIN*Hin*Win;
  int xx = threadIdx.x & 15, ys = threadIdx.x >> 4;

  float4 vv[5];
  auto ld = [&](int ci){
    const float* ip = inb + (size_t)ci*Hin*Win;
    float m = msm[ci], is = ism[ci];
    #pragma unroll
    for (int q=0;q<5;q++){
      int u = threadIdx.x + q*256;
      if (u < 1089){
        int r = u/33, k = u - r*33;
        int iy = IY0 + r;
        bool okY = (unsigned)iy < (unsigned)Hin;
        if (k < 32){
          float4 v = {0.f,0.f,0.f,0.f};
          if (okY){
            v = *(const float4*)(ip + (size_t)iy*Win + GX + 4*k);
            v.x = fmaxf((v.x-m)*is, 0.f);
            v.y = fmaxf((v.y-m)*is, 0.f);
            v.z = fmaxf((v.z-m)*is, 0.f);
            v.w = fmaxf((v.w-m)*is, 0.f);
          }
          vv[q] = v;
        } else {
          float hv = 0.f;
          if (okY && X0 > 0) hv = fmaxf((ip[(size_t)iy*Win + GX-1]-m)*is, 0.f);
          vv[q].x = hv;
        }
      }
    }
  };
  auto st = [&](int buf){
    float* tb = tile[buf];
    #pragma unroll
    for (int q=0;q<5;q++){
      int u = threadIdx.x + q*256;
      if (u < 1089){
        int r = u/33, k = u - r*33;
        float* row = tb + r*TSTR;
        if (k < 32){
          float4 v = vv[q];
          float2 e = {v.x, v.z};
          *(float2*)(row + 2*k) = e;
          row[ODD + 2*k+1] = v.y;
          row[ODD + 2*k+2] = v.w;
        } else {
          row[ODD] = vv[q].x;
        }
      }
    }
  };

  float acc[COT][4];
  #pragma unroll
  for (int j=0;j<COT;j++){ float bv = bias[co0+j];
    #pragma unroll
    for (int p=0;p<4;p++) acc[j][p]=bv; }

  ld(0); st(0);
  for (int ci=0; ci<CIN; ++ci){
    __syncthreads();
    if (ci+1 < CIN) ld(ci+1);
    {
      const float* tb = tile[ci&1];
      float ev[3][4], od[3][5];
      #pragma unroll
      for (int ky=0;ky<3;ky++){
        const float* rowp = tb + (2*ys+ky)*TSTR;
        float4 e4 = *(const float4*)(rowp + 4*xx);
        float4 o4 = *(const float4*)(rowp + ODD + 4*xx);
        float o1  = rowp[ODD + 4*xx + 4];
        ev[ky][0]=e4.x; ev[ky][1]=e4.y; ev[ky][2]=e4.z; ev[ky][3]=e4.w;
        od[ky][0]=o4.x; od[ky][1]=o4.y; od[ky][2]=o4.z; od[ky][3]=o4.w; od[ky][4]=o1;
      }
      #pragma unroll
      for (int j=0;j<COT;j++){
        const float* wj = w + ((size_t)(co0+j)*CIN + ci)*9;   // uniform -> s_load
        float wk[9];
        #pragma unroll
        for (int k=0;k<9;k++) wk[k] = wj[k];
        #pragma unroll
        for (int p=0;p<4;p++){
          #pragma unroll
          for (int ky=0;ky<3;ky++){
            acc[j][p] = fmaf(od[ky][p],   wk[ky*3+0], acc[j][p]);
            acc[j][p] = fmaf(ev[ky][p],   wk[ky*3+1], acc[j][p]);
            acc[j][p] = fmaf(od[ky][p+1], wk[ky*3+2], acc[j][p]);
          }
        }
      }
    }
    if (ci+1 < CIN) st((ci+1)&1);
  }

  float* ob = out + ((size_t)b*Cout + co0)*Hout*Wout + (size_t)(Y0+ys)*Wout + X0 + 4*xx;
  #pragma unroll
  for (int j=0;j<COT;j++){
    float4 v = {acc[j][0],acc[j][1],acc[j][2],acc[j][3]};
    *(float4*)(ob + (size_t)j*Hout*Wout) = v;
  }
  // ---- stats ----
  float ss[COT], qq[COT];
  #pragma unroll
  for (int j=0;j<COT;j++){
    float a=0.f,c=0.f;
    #pragma unroll
    for (int p=0;p<4;p++){ a+=acc[j][p]; c=fmaf(acc[j][p],acc[j][p],c); }
    ss[j]=a; qq[j]=c;
  }
  #pragma unroll
  for (int o=32;o>0;o>>=1){
    #pragma unroll
    for (int j=0;j<COT;j++){ ss[j]+=__shfl_down(ss[j],o); qq[j]+=__shfl_down(qq[j],o); }
  }
  int lane = threadIdx.x & 63, wid = threadIdx.x >> 6;
  if (lane==0){
    #pragma unroll
    for (int j=0;j<COT;j++){ red[wid][j]=ss[j]; red[wid][COT+j]=qq[j]; }
  }
  __syncthreads();
  if (threadIdx.x < COT){
    int j = threadIdx.x;
    float a = red[0][j]+red[1][j]+red[2][j]+red[3][j];
    float c = red[0][COT+j]+red[1][COT+j]+red[2][COT+j]+red[3][COT+j];
    float* sp = &statOut[((size_t)b*Cout + co0 + j)*2];
    atomicAdd(sp, a); atomicAdd(sp+1, c);
  }
}

// ---------------- 3x3 stride-2 conv, 32x16 tile (R20; d3). R25 xcd-adjacent ----------------
template<int CIN, int COT>
__global__ __launch_bounds__(256,4) void conv3s2_lds(const float* __restrict__ in,
    const float* __restrict__ w, const float* __restrict__ bias, float* __restrict__ out,
    int Hin, int Win, const float* __restrict__ statIn, float* __restrict__ statOut){
  const int Cout = 2*CIN;
  const int CG = Cout/COT;
  const int TSTR = 72;
  __shared__ float msm[CIN], ism[CIN];
  __shared__ __align__(16) float tile[2][33*TSTR];
  __shared__ float red[4][2*COT];
  int Hout = Hin>>1, Wout = Win>>1;
  int xtn = Wout>>5, ytn = Hout>>4;
  int NT = BATCH*xtn*ytn;                // multiple of 8
  int bid = blockIdx.x;
  int xcd = bid & 7; int s = bid >> 3;
  int cgi = s % CG;  int tq = s / CG;
  int t = xcd*(NT>>3) + tq;
  int xt  = t % xtn;  t /= xtn;
  int yt  = t % ytn;  int b = t / ytn;
  int co0 = cgi*COT;
  int X0 = xt<<5, Y0 = yt<<4;
  int IY0 = 2*Y0-1, GX = X0<<1;
  {
    float invHW = 1.f/(float)(Hin*Win);
    for (int t2=threadIdx.x; t2<CIN; t2+=256){
      float s0  = statIn[((size_t)b*CIN + t2)*2];
      float s2 = statIn[((size_t)b*CIN + t2)*2+1];
      float m = s0*invHW;
      float v = fmaxf(s2*invHW - m*m, 0.f);
      msm[t2] = m; ism[t2] = rsqrtf(v + EPS);
    }
  }
  __syncthreads();
  const float* inb = in + (size_t)b*CIN*Hin*Win;
  int xx = threadIdx.x & 31, ys = threadIdx.x >> 5;

  float4 vv[3]; float hh[3];
  auto ld = [&](int ci){
    const float* ip = inb + (size_t)ci*Hin*Win;
    float m = msm[ci], is = ism[ci];
    #pragma unroll
    for (int q=0;q<3;q++){
      int u = threadIdx.x + q*256;
      if (u < 561){
        int r = u/17, k = u - r*17;
        int iy = IY0 + r;
        bool okY = (unsigned)iy < (unsigned)Hin;
        if (k < 16){
          float4 v = {0.f,0.f,0.f,0.f};
          if (okY){
            v = *(const float4*)(ip + (size_t)iy*Win + GX + 4*k);
            v.x = fmaxf((v.x-m)*is, 0.f);
            v.y = fmaxf((v.y-m)*is, 0.f);
            v.z = fmaxf((v.z-m)*is, 0.f);
            v.w = fmaxf((v.w-m)*is, 0.f);
          }
          vv[q] = v;
        } else {
          float hv = 0.f;
          if (okY && X0 > 0) hv = fmaxf((ip[(size_t)iy*Win + GX-1]-m)*is, 0.f);
          hh[q] = hv;
        }
      }
    }
  };
  auto st = [&](int buf){
    float* tb = tile[buf];
    #pragma unroll
    for (int q=0;q<3;q++){
      int u = threadIdx.x + q*256;
      if (u < 561){
        int r = u/17, k = u - r*17;
        float* row = tb + r*TSTR;
        if (k < 16){
          float4 v = vv[q];
          row[2*k]        = v.x;
          row[2*k+1]      = v.z;
          row[36+2*k+1]   = v.y;
          row[36+2*k+2]   = v.w;
        } else {
          row[36] = hh[q];
        }
      }
    }
  };

  float acc[COT][2];
  #pragma unroll
  for (int j=0;j<COT;j++){ float bv = bias[co0+j]; acc[j][0]=bv; acc[j][1]=bv; }

  ld(0); st(0);
  for (int ci=0; ci<CIN; ++ci){
    __syncthreads();
    if (ci+1 < CIN) ld(ci+1);
    {
      const float* tb = tile[ci&1];
      float rv[2][3][3];
      #pragma unroll
      for (int g=0;g<2;g++){
        int rb = (ys + (g<<3))<<1;
        #pragma unroll
        for (int ky=0;ky<3;ky++){
          const float* er = tb + (rb+ky)*TSTR;
          const float* od = er + 36;
          rv[g][ky][0]=od[xx]; rv[g][ky][1]=er[xx]; rv[g][ky][2]=od[xx+1];
        }
      }
      #pragma unroll
      for (int j=0;j<COT;j++){
        const float* wj = w + ((size_t)(co0+j)*CIN + ci)*9;   // uniform -> s_load
        float wk[9];
        #pragma unroll
        for (int k=0;k<9;k++) wk[k] = wj[k];
        #pragma unroll
        for (int g=0;g<2;g++)
          #pragma unroll
          for (int ky=0;ky<3;ky++)
            #pragma unroll
            for (int kx=0;kx<3;kx++)
              acc[j][g] = fmaf(rv[g][ky][kx], wk[ky*3+kx], acc[j][g]);
      }
    }
    if (ci+1 < CIN) st((ci+1)&1);
  }

  float* ob = out + ((size_t)b*Cout + co0)*Hout*Wout;
  #pragma unroll
  for (int j=0;j<COT;j++)
    #pragma unroll
    for (int g=0;g<2;g++){
      int oy = ys + (g<<3);
      ob[(size_t)j*Hout*Wout + (Y0+oy)*Wout + X0 + xx] = acc[j][g];
    }
  // ---- stats ----
  float ss[COT], qq[COT];
  #pragma unroll
  for (int j=0;j<COT;j++){
    float a = acc[j][0] + acc[j][1];
    float c = fmaf(acc[j][0],acc[j][0], acc[j][1]*acc[j][1]);
    ss[j]=a; qq[j]=c;
  }
  #pragma unroll
  for (int o=32;o>0;o>>=1){
    #pragma unroll
    for (int j=0;j<COT;j++){ ss[j]+=__shfl_down(ss[j],o); qq[j]+=__shfl_down(qq[j],o); }
  }
  int lane = threadIdx.x & 63, wid = threadIdx.x >> 6;
  if (lane==0){
    #pragma unroll
    for (int j=0;j<COT;j++){ red[wid][j]=ss[j]; red[wid][COT+j]=qq[j]; }
  }
  __syncthreads();
  if (threadIdx.x < COT){
    int j = threadIdx.x;
    float a = red[0][j]+red[1][j]+red[2][j]+red[3][j];
    float c = red[0][COT+j]+red[1][COT+j]+red[2][COT+j]+red[3][COT+j];
    float* sp = &statOut[((size_t)b*Cout + co0 + j)*2];
    atomicAdd(sp, a); atomicAdd(sp+1, c);
  }
}

// ---------------- tconv k=3 s=2 p=1 op=1; LDS-staged. R25 xcd-adjacent ----------------
template<int CIN, int COT>
__global__ __launch_bounds__(256,4) void tconv3_lds(const float* __restrict__ in,
    const float* __restrict__ w, const float* __restrict__ bias, float* __restrict__ out,
    int Hin, int Win, const float* __restrict__ statIn, float* __restrict__ statOut){
  const int Cout = CIN/2;
  const int CG = Cout/COT;
  const int TSTR = 36;
  __shared__ float msm[CIN], ism[CIN];
  __shared__ __align__(16) float tile[2][17*TSTR];
  __shared__ float red[4][2*COT];
  int Hout = Hin<<1, Wout = Win<<1;
  int xtn = Win>>5, ytn = Hin>>4;
  int NT = BATCH*xtn*ytn;                // multiple of 8
  int bid = blockIdx.x;
  int xcd = bid & 7; int s = bid >> 3;
  int cgi = s % CG;  int tq = s / CG;
  int t = xcd*(NT>>3) + tq;
  int xt  = t % xtn;  t /= xtn;
  int yt  = t % ytn;  int b = t / ytn;
  int co0 = cgi*COT;
  int X0 = xt<<5, Y0 = yt<<4;
  {
    float invHW = 1.f/(float)(Hin*Win);
    for (int t2=threadIdx.x; t2<CIN; t2+=256){
      float s0  = statIn[((size_t)b*CIN + t2)*2];
      float s2 = statIn[((size_t)b*CIN + t2)*2+1];
      float m = s0*invHW;
      float v = fmaxf(s2*invHW - m*m, 0.f);
      msm[t2] = m; ism[t2] = rsqrtf(v + EPS);
    }
  }
  __syncthreads();
  const float* inb = in + (size_t)b*CIN*Hin*Win;
  int xx = threadIdx.x & 31, ys = threadIdx.x >> 5;

  float4 sv; float sh;
  auto ld = [&](int ci){
    const float* ip = inb + (size_t)ci*Hin*Win;
    float m = msm[ci], is = ism[ci];
    int u = threadIdx.x;
    if (u < 153){
      int r = u/9, k = u - r*9;
      int iy = Y0 + r;
      bool okY = iy < Hin;
      if (k < 8){
        float4 v = {0.f,0.f,0.f,0.f};
        if (okY){
          v = *(const float4*)(ip + (size_t)iy*Win + X0 + 4*k);
          v.x = fmaxf((v.x-m)*is, 0.f);
          v.y = fmaxf((v.y-m)*is, 0.f);
          v.z = fmaxf((v.z-m)*is, 0.f);
          v.w = fmaxf((v.w-m)*is, 0.f);
        }
        sv = v;
      } else {
        float hv = 0.f;
        int xc = X0 + 32;
        if (okY && xc < Win) hv = fmaxf((ip[(size_t)iy*Win + xc]-m)*is, 0.f);
        sh = hv;
      }
    }
  };
  auto st = [&](int buf){
    int u = threadIdx.x;
    if (u < 153){
      int r = u/9, k = u - r*9;
      if (k < 8) *(float4*)(tile[buf] + r*TSTR + 4*k) = sv;
      else tile[buf][r*TSTR + 32] = sh;
    }
  };

  float acc[COT][2][2][2];
  #pragma unroll
  for (int j=0;j<COT;j++){ float bv = bias[co0+j];
    #pragma unroll
    for (int g=0;g<2;g++)
      #pragma unroll
      for (int oy=0;oy<2;oy++){ acc[j][g][oy][0]=bv; acc[j][g][oy][1]=bv; } }

  ld(0); st(0);
  for (int ci=0; ci<CIN; ++ci){
    __syncthreads();
    if (ci+1 < CIN) ld(ci+1);
    {
      const float* tb = tile[ci&1];
      float v[2][2][2];
      #pragma unroll
      for (int g=0;g<2;g++){
        int rb = ys + (g<<3);
        const float* t0 = tb + rb*TSTR + xx;
        v[g][0][0]=t0[0]; v[g][0][1]=t0[1];
        v[g][1][0]=t0[TSTR]; v[g][1][1]=t0[TSTR+1];
      }
      #pragma unroll
      for (int j=0;j<COT;j++){
        const float* wj = w + ((size_t)ci*Cout + co0+j)*9;   // uniform -> s_load
        float wk[9];
        #pragma unroll
        for (int k=0;k<9;k++) wk[k] = wj[k];
        #pragma unroll
        for (int g=0;g<2;g++){
          float v00=v[g][0][0], v01=v[g][0][1], v10=v[g][1][0], v11=v[g][1][1];
          acc[j][g][0][0] = fmaf(v00, wk[4], acc[j][g][0][0]);
          acc[j][g][0][1] = fmaf(v00, wk[5], fmaf(v01, wk[3], acc[j][g][0][1]));
          acc[j][g][1][0] = fmaf(v00, wk[7], fmaf(v10, wk[1], acc[j][g][1][0]));
          acc[j][g][1][1] = fmaf(v00, wk[8], fmaf(v01, wk[6],
                             fmaf(v10, wk[2], fmaf(v11, wk[0], acc[j][g][1][1]))));
        }
      }
    }
    if (ci+1 < CIN) st((ci+1)&1);
  }

  float* ob = out + ((size_t)b*Cout + co0)*Hout*Wout;
  #pragma unroll
  for (int j=0;j<COT;j++)
    #pragma unroll
    for (int g=0;g<2;g++)
      #pragma unroll
      for (int oy=0;oy<2;oy++){
        int orow = 2*(Y0 + ys + (g<<3)) + oy;
        float2 v2 = {acc[j][g][oy][0], acc[j][g][oy][1]};
        *(float2*)(ob + (size_t)j*Hout*Wout + (size_t)orow*Wout + 2*(X0+xx)) = v2;
      }
  // ---- stats ----
  float ss[COT], qq[COT];
  #pragma unroll
  for (int j=0;j<COT;j++){
    float a=0.f,c=0.f;
    #pragma unroll
    for (int g=0;g<2;g++)
      #pragma unroll
      for (int oy=0;oy<2;oy++)
        #pragma unroll
        for (int ox=0;ox<2;ox++){ float u=acc[j][g][oy][ox]; a+=u; c=fmaf(u,u,c); }
    ss[j]=a; qq[j]=c;
  }
  #pragma unroll
  for (int o=32;o>0;o>>=1){
    #pragma unroll
    for (int j=0;j<COT;j++){ ss[j]+=__shfl_down(ss[j],o); qq[j]+=__shfl_down(qq[j],o); }
  }
  int lane = threadIdx.x & 63, wid = threadIdx.x >> 6;
  if (lane==0){
    #pragma unroll
    for (int j=0;j<COT;j++){ red[wid][j]=ss[j]; red[wid][COT+j]=qq[j]; }
  }
  __syncthreads();
  if (threadIdx.x < COT){
    int j = threadIdx.x;
    float a = red[0][j]+red[1][j]+red[2][j]+red[3][j];
    float c = red[0][COT+j]+red[1][COT+j]+red[2][COT+j]+red[3][COT+j];
    float* sp = &statOut[((size_t)b*Cout + co0 + j)*2];
    atomicAdd(sp, a); atomicAdd(sp+1, c);
  }
}

// ---------------- broadcast means back ----------------
__global__ void pool_bcast(float* __restrict__ out, const int* __restrict__ imap,
                           const float* __restrict__ sums, const float* __restrict__ cnts){
  const int P = 512*512;
  int b = blockIdx.y;
  __shared__ float lm[96];
  if (threadIdx.x < 96){
    int id = threadIdx.x/3;
    lm[threadIdx.x] = sums[b*96+threadIdx.x] / fmaxf(cnts[b*32+id], 1.0f);
  }
  __syncthreads();
  const int* mb = imap + (size_t)b*P;
  float* ob = out + (size_t)b*3*P;
  for (int p = blockIdx.x*blockDim.x + threadIdx.x; p < P; p += gridDim.x*blockDim.x){
    int id = mb[p];
    ob[p]     = lm[id*3+0];
    ob[P+p]   = lm[id*3+1];
    ob[2*P+p] = lm[id*3+2];
  }
}

static inline int cdiv(int a, int b){ return (a+b-1)/b; }

extern "C" void kernel_launch(void* const* d_in, const int* in_sizes, int n_in,
                              void* d_out, int out_size, void* d_ws, size_t ws_size,
                              hipStream_t stream) {
  const float* x    = (const float*)d_in[0];
  const int*   imap = (const int*)d_in[1];
  const float* w_in = (const float*)d_in[2];
  const float* b_in = (const float*)d_in[3];
  const float *wd[4], *bd[4], *wu[4], *bu[4];
  for (int i=0;i<4;i++){ wd[i]=(const float*)d_in[4+2*i];  bd[i]=(const float*)d_in[5+2*i]; }
  for (int i=0;i<4;i++){ wu[i]=(const float*)d_in[12+2*i]; bu[i]=(const float*)d_in[13+2*i]; }
  const float* w_out = (const float*)d_in[20];
  const float* b_out = (const float*)d_in[21];
  float* out = (float*)d_out;

  char* ws = (char*)d_ws;
  float* A     = (float*)ws;
  float* Bb    = (float*)(ws + (size_t)134217728);
  float* stats = (float*)(ws + (size_t)134217728 + (size_t)67108864);
  float* stLin = stats;          // 8*16*2  = 256
  float* std0  = stLin + 256;    // 8*32*2  = 512
  float* std1  = std0  + 512;    // 8*64*2  = 1024
  float* std2  = std1  + 1024;   // 8*128*2 = 2048
  float* std3  = std2  + 2048;   // 8*256*2 = 4096
  float* stu0  = std3  + 4096;   // 8*128*2 = 2048
  float* stu1  = stu0  + 2048;   // 8*64*2  = 1024
  float* stu2  = stu1  + 1024;   // 8*32*2  = 512
  float* stu3  = stu2  + 512;    // 8*16*2  = 256
  float* sums  = stu3  + 256;    // [8][32][3] = 768
  float* cnts  = sums  + 768;    // [8][32]    = 256
  hipMemsetAsync(stats, 0, (size_t)(11776 + 1024)*sizeof(float), stream);

  // conv_in: 3 -> 16 @ 512x512
  conv7_in_t<<<2048, 256, 0, stream>>>(x, w_in, b_in, A, stLin);

  // down path: R21 tiles + R25 xcd-adjacent decomposition; d3 -> R20 kernel
  conv3s2_w64<16,8><<<2048, 256, 0, stream>>>(A,  wd[0], bd[0], Bb, 512, 512, stLin, std0);
  conv3s2_w64<32,8><<<1024, 256, 0, stream>>>(Bb, wd[1], bd[1], A,  256, 256, std0, std1);
  conv3s2_w64<64,4><<<1024, 256, 0, stream>>>(A,  wd[2], bd[2], Bb, 128, 128, std1, std2);
  conv3s2_lds<128,4><<<1024, 256, 0, stream>>>(Bb, wd[3], bd[3], A,  64,  64, std2, std3);

  // up path: LDS-staged + R25 xcd-adjacent decomposition
  tconv3_lds<256,2><<<1024, 256, 0, stream>>>(A,  wu[0], bu[0], Bb, 32, 32, std3, stu0);
  tconv3_lds<128,4><<<1024, 256, 0, stream>>>(Bb, wu[1], bu[1], A,  64, 64, stu0, stu1);
  tconv3_lds<64,4><<<2048, 256, 0, stream>>>(A,  wu[2], bu[2], Bb, 128, 128, stu1, stu2);
  tconv3_lds<32,4><<<4096, 256, 0, stream>>>(Bb, wu[3], bu[3], A,  256, 256, stu2, stu3);

  // conv_out: 16 -> 3 @ 512x512 + tanh + fused scatter-sum pooling (R24)
  conv7_out_t<<<2048, 256, 0, stream>>>(A, w_out, b_out, out, stu3, imap, sums, cnts);

  // broadcast means back
  pool_bcast<<<dim3(128,BATCH),256,0,stream>>>(out, imap, sums, cnts);
}